// Round 2
// baseline (297.088 us; speedup 1.0000x reference)
//
#include <hip/hip_runtime.h>

#define N_NODES 50000
#define N_EDGES 600000
#define C 128
#define STRIPS 3125          // N_NODES / 16
#define GROUPS 3125          // R8: 1 strip (16 nodes) per wave -> LDS 17.4KB/block
#define N_TASKS 4            // 0 rel(L2) 1 hh0(L1) 2 hh1(L0) 3 loop(L2)

typedef __bf16 bf16;
typedef __attribute__((ext_vector_type(8))) __bf16 bf16x8;
typedef __attribute__((ext_vector_type(4))) __bf16 bf16x4;
typedef __attribute__((ext_vector_type(2))) __bf16 bf16x2;
typedef __attribute__((ext_vector_type(4))) float f32x4;
typedef __attribute__((ext_vector_type(2))) float f32x2;

struct PtrsV { const void* p[8]; };

// ---------------------------------------------------------------------------
// Dtype detection (verified R2-R6) + deg zeroing. flags 1 = fp32, 0 = bf16.
// ---------------------------------------------------------------------------
__device__ __forceinline__ int bf16_wild(unsigned short w) {
    int exp = (w >> 7) & 0xFF;
    int mant = w & 0x7F;
    if (exp == 0xFF) return 1;
    if (exp >= 133) return 1;                // |x| >= 64
    if (exp == 0) return mant != 0 ? 1 : 0;  // denormal
    if (exp <= 114) return 1;                // 0 < |x| < 2^-12
    return 0;
}

__global__ void __launch_bounds__(256) detect_zero_kernel(
    const unsigned short* __restrict__ emb,
    const unsigned short* __restrict__ w,
    const unsigned short* __restrict__ b,
    const unsigned short* __restrict__ hc,
    int* __restrict__ flags, int* __restrict__ deg)
{
    if (blockIdx.x == 0) {
        int lane = threadIdx.x;
        if (lane >= 64) return;
        int ce = 0, cw = 0, cb = 0, ch = 0;
        for (int j = 0; j < 4; ++j) {
            ce += bf16_wild(emb[lane * 4 + j]);
            cw += bf16_wild(w[lane * 4 + j]);
        }
        for (int j = 0; j < 2; ++j) cb += bf16_wild(b[lane * 2 + j]);
        if (lane < 3) ch = bf16_wild(hc[lane]);
        for (int off = 32; off > 0; off >>= 1) {
            ce += __shfl_down(ce, off);
            cw += __shfl_down(cw, off);
            cb += __shfl_down(cb, off);
            ch += __shfl_down(ch, off);
        }
        if (lane == 0) {
            int wf = (cw >= 16) ? 1 : 0;
            flags[0] = (ce >= 16) ? 1 : 0;
            flags[1] = wf;
            flags[2] = (cb >= 8) ? 1 : 0;
            flags[3] = (ch > 0) ? 1 : wf;
        }
    } else {
        int i = (blockIdx.x - 1) * 256 + threadIdx.x;
        if (i < N_NODES) deg[i] = 0;
    }
}

// ---------------------------------------------------------------------------
// Pack weights into MFMA B-fragment order (verified R2-R6).
// Frag index within matrix (as bf16x8): kk*512 + n0*64 + lane.
// Slots 4,5 are the second hh matrix (+16384 elems / +128 bias).
// ---------------------------------------------------------------------------
__global__ void __launch_bounds__(256) pack_kernel(
    PtrsV wmats, PtrsV bvecs, const void* hc_raw,
    const int* __restrict__ flags,
    bf16* __restrict__ pw, float* __restrict__ cbias, float* __restrict__ ccoef)
{
    int tid = blockIdx.x * 256 + threadIdx.x;
    int wf = flags[1], bfl = flags[2], hf = flags[3];
    if (tid < 8 * 16384) {
        int m    = tid >> 14;
        int r    = tid & 16383;
        int j    = r & 7;
        int lane = (r >> 3) & 63;
        int n0   = (r >> 9) & 7;
        int kk   = r >> 12;
        int k = kk * 32 + (lane >> 4) * 8 + j;
        int n = n0 * 16 + (lane & 15);
        int idx = k * C + n + ((m == 4 || m == 5) ? 16384 : 0);
        float v = wf ? ((const float*)wmats.p[m])[idx]
                     : (float)((const bf16*)wmats.p[m])[idx];
        pw[tid] = (bf16)v;
    } else if (tid < 8 * 16384 + 1024) {
        int j = tid - 8 * 16384;
        int m = j >> 7, n = j & 127;
        int idx = n + ((m == 4 || m == 5) ? 128 : 0);
        float v = bfl ? ((const float*)bvecs.p[m])[idx]
                      : (float)((const bf16*)bvecs.p[m])[idx];
        cbias[j] = v;
    } else if (tid < 8 * 16384 + 1024 + 3) {
        int i = tid - (8 * 16384 + 1024);
        float v = hf ? ((const float*)hc_raw)[i]
                     : (float)((const bf16*)hc_raw)[i];
        ccoef[i] = v;
    }
}

// ---------------------------------------------------------------------------
// MLP v6 (R8): per-wave 16-node group (1 strip). R7 (2 strips, 34.8KB LDS)
// hit the LDS occupancy wall at 4 blocks/CU (Occ 32%, MfmaUtil 7%,
// VALUBusy 10% => still latency-bound). VGPR=52 means the register file
// allows 8 waves/SIMD; only LDS caps occupancy. 1 strip -> 17.4KB LDS ->
// 8 blocks/CU = 32 waves (100% cap). STRIPS%1==0 so all predication gone.
// B-fragment L2 traffic doubles (~800MB) but stays <50% of L2 ceiling.
// All MFMA/LDS layouts identical to the R2-R6 verified ones.
// ---------------------------------------------------------------------------
__global__ __launch_bounds__(256, 4) void mlp_kernel(
    const void* __restrict__ emb_raw,    // [3][N][C] fp32 or bf16
    const bf16* __restrict__ pw,         // packed weights [8][16384]
    const float* __restrict__ cbias,     // [8][128]
    const float* __restrict__ ccoef,     // [3]
    const int* __restrict__ flags,
    bf16* __restrict__ h,                // [3][N][C], premultiplied by coef
    bf16* __restrict__ hs)               // [N][C] self term (loop MLP)
{
    __shared__ bf16 sH[4][16][136];      // 17.4 KB -> 8 blocks/CU (wave-slot cap)
    const int tid  = threadIdx.x;
    const int wave = tid >> 6, lane = tid & 63;
    const int wid  = blockIdx.x * 4 + wave;     // 0..12499
    if (wid >= N_TASKS * GROUPS) return;
    const int task = wid & 3;
    const int grp  = wid >> 2;                  // 0..3124 == strip index
    const int lrow = lane & 15, lquad = lane >> 4;
    bf16 (*sh)[136] = sH[wave];

    const int m1_of[4] = {0, 2, 4, 6};
    const int ly_of[4] = {2, 1, 0, 2};
    const int m1 = m1_of[task];
    const bf16x8* w1v = (const bf16x8*)(pw + (size_t)m1 * 16384);
    const bf16x8* w2v = w1v + 2048;
    const float oscale = (task == 0) ? ccoef[0] : (task == 1) ? ccoef[1]
                       : (task == 2) ? ccoef[2] : 1.0f;
    bf16* outp = (task == 3) ? hs : (h + (size_t)task * N_NODES * C);
    const int emb_f32 = flags[0];
    const size_t lbase = (size_t)ly_of[task] * N_NODES * C;

    const int s0 = grp;                         // strip, always valid

    // ---- biases for this lane's columns ----
    float b1f[8], b2f[8];
    #pragma unroll
    for (int n0 = 0; n0 < 8; ++n0) {
        b1f[n0] = cbias[m1 * 128 + n0 * 16 + lrow];
        b2f[n0] = cbias[(m1 + 1) * 128 + n0 * 16 + lrow];
    }

    // ---- A-fragments for the strip, direct from global ----
    // A[m=lane&15][k=quad*8+j].
    bf16x8 af[4];
    {
        size_t xb = lbase + (size_t)(s0 * 16 + lrow) * C + lquad * 8;
        if (emb_f32) {
            const float* xf = (const float*)emb_raw + xb;
            #pragma unroll
            for (int kk = 0; kk < 4; ++kk) {
                f32x4 u0 = *(const f32x4*)(xf + kk * 32);
                f32x4 u1 = *(const f32x4*)(xf + kk * 32 + 4);
                bf16x8 v;
                v[0]=(bf16)u0[0]; v[1]=(bf16)u0[1]; v[2]=(bf16)u0[2]; v[3]=(bf16)u0[3];
                v[4]=(bf16)u1[0]; v[5]=(bf16)u1[1]; v[6]=(bf16)u1[2]; v[7]=(bf16)u1[3];
                af[kk] = v;
            }
        } else {
            const bf16* x16 = (const bf16*)emb_raw + xb;
            #pragma unroll
            for (int kk = 0; kk < 4; ++kk)
                af[kk] = *(const bf16x8*)(x16 + kk * 32);
        }
    }

    // ---- GEMM1: hidden = relu(X @ W1 + b1) -> sh ----
    #pragma unroll
    for (int n0 = 0; n0 < 8; ++n0) {
        bf16x8 bv0 = w1v[0 * 512 + n0 * 64 + lane];
        bf16x8 bv1 = w1v[1 * 512 + n0 * 64 + lane];
        bf16x8 bv2 = w1v[2 * 512 + n0 * 64 + lane];
        bf16x8 bv3 = w1v[3 * 512 + n0 * 64 + lane];
        int n = n0 * 16 + lrow;
        float bias = b1f[n0];
        f32x4 a4 = {0.f, 0.f, 0.f, 0.f};
        a4 = __builtin_amdgcn_mfma_f32_16x16x32_bf16(af[0], bv0, a4, 0, 0, 0);
        a4 = __builtin_amdgcn_mfma_f32_16x16x32_bf16(af[1], bv1, a4, 0, 0, 0);
        a4 = __builtin_amdgcn_mfma_f32_16x16x32_bf16(af[2], bv2, a4, 0, 0, 0);
        a4 = __builtin_amdgcn_mfma_f32_16x16x32_bf16(af[3], bv3, a4, 0, 0, 0);
        #pragma unroll
        for (int r = 0; r < 4; ++r) {
            float v = a4[r] + bias;
            v = v > 0.f ? v : 0.f;
            sh[lquad * 4 + r][n] = (bf16)v;
        }
    }

    // ---- read ALL GEMM2 A-frags (then sh is free to overwrite) ----
    bf16x8 ah[4];
    #pragma unroll
    for (int kk = 0; kk < 4; ++kk)
        ah[kk] = *(const bf16x8*)(&sh[lrow][kk * 32 + lquad * 8]);

    // ---- GEMM2: out = oscale*(hidden @ W2 + b2) -> sh ----
    #pragma unroll
    for (int n0 = 0; n0 < 8; ++n0) {
        bf16x8 bv0 = w2v[0 * 512 + n0 * 64 + lane];
        bf16x8 bv1 = w2v[1 * 512 + n0 * 64 + lane];
        bf16x8 bv2 = w2v[2 * 512 + n0 * 64 + lane];
        bf16x8 bv3 = w2v[3 * 512 + n0 * 64 + lane];
        int n = n0 * 16 + lrow;
        float bias = b2f[n0];
        f32x4 a4 = {0.f, 0.f, 0.f, 0.f};
        a4 = __builtin_amdgcn_mfma_f32_16x16x32_bf16(ah[0], bv0, a4, 0, 0, 0);
        a4 = __builtin_amdgcn_mfma_f32_16x16x32_bf16(ah[1], bv1, a4, 0, 0, 0);
        a4 = __builtin_amdgcn_mfma_f32_16x16x32_bf16(ah[2], bv2, a4, 0, 0, 0);
        a4 = __builtin_amdgcn_mfma_f32_16x16x32_bf16(ah[3], bv3, a4, 0, 0, 0);
        #pragma unroll
        for (int r = 0; r < 4; ++r)
            sh[lquad * 4 + r][n] = (bf16)((a4[r] + bias) * oscale);
    }

    // ---- coalesced store of 16 rows ----
    {
        int row = lane >> 2;
        int cs  = (lane & 3) * 32;
        bf16* dst = outp + (size_t)(s0 * 16) * C;
        #pragma unroll
        for (int j = 0; j < 4; ++j) {
            bf16x8 v = *(const bf16x8*)(&sh[row][cs + j * 8]);
            *(bf16x8*)(dst + (size_t)row * C + cs + j * 8) = v;
        }
    }
}

// ---------------------------------------------------------------------------
// CSR build: histogram, 3-phase scan, bucket fill (verified R5/R6).
// ---------------------------------------------------------------------------
__global__ void __launch_bounds__(256) hist_kernel(
    const int* __restrict__ erow, int* __restrict__ deg)
{
    int e = blockIdx.x * 256 + threadIdx.x;
    if (e >= N_EDGES) return;
    atomicAdd(&deg[erow[e]], 1);
}

__device__ __forceinline__ int wave_incl_scan(int v, int lane) {
    int x = v;
    #pragma unroll
    for (int d = 1; d < 64; d <<= 1) {
        int t = __shfl_up(x, d);
        if (lane >= d) x += t;
    }
    return x;
}

__global__ void __launch_bounds__(256) scanA_kernel(
    const int* __restrict__ deg, int* __restrict__ offsets, int* __restrict__ btot)
{
    __shared__ int swave[4];
    int b = blockIdx.x, tid = threadIdx.x;
    int i = b * 256 + tid;
    int lane = tid & 63, wv = tid >> 6;
    int v = (i < N_NODES) ? deg[i] : 0;
    int x = wave_incl_scan(v, lane);
    if (lane == 63) swave[wv] = x;
    __syncthreads();
    int w0 = swave[0], w1 = swave[1], w2 = swave[2], w3 = swave[3];
    int wp = (wv > 0 ? w0 : 0) + (wv > 1 ? w1 : 0) + (wv > 2 ? w2 : 0);
    if (i < N_NODES) offsets[i] = wp + x - v;
    if (tid == 0) btot[b] = w0 + w1 + w2 + w3;
}

__global__ void __launch_bounds__(256) scanB_kernel(
    const int* __restrict__ btot, int* __restrict__ bbase, int nblk)
{
    __shared__ int swave[4];
    int tid = threadIdx.x;
    int lane = tid & 63, wv = tid >> 6;
    int v = (tid < nblk) ? btot[tid] : 0;
    int x = wave_incl_scan(v, lane);
    if (lane == 63) swave[wv] = x;
    __syncthreads();
    int w0 = swave[0], w1 = swave[1], w2 = swave[2], w3 = swave[3];
    int wp = (wv > 0 ? w0 : 0) + (wv > 1 ? w1 : 0) + (wv > 2 ? w2 : 0);
    if (tid < nblk) bbase[tid] = wp + x - v;
}

__global__ void __launch_bounds__(256) scanC_kernel(
    const int* __restrict__ bbase, int* __restrict__ offsets, int* __restrict__ cursor)
{
    int i = blockIdx.x * 256 + threadIdx.x;
    if (i < N_NODES) {
        int o = offsets[i] + bbase[blockIdx.x];
        offsets[i] = o;
        cursor[i] = o;
    }
    if (i == 0) offsets[N_NODES] = N_EDGES;
}

__global__ void __launch_bounds__(256) fill_kernel(
    const int* __restrict__ erow, const int* __restrict__ ecol,
    const int* __restrict__ ew,
    int* __restrict__ cursor, int* __restrict__ edata)
{
    int e = blockIdx.x * 256 + threadIdx.x;
    if (e >= N_EDGES) return;
    int dst = erow[e];
    int pos = atomicAdd(&cursor[dst], 1);
    edata[pos] = (ecol[e] << 2) | (ew[e] - 1);
}

// ---------------------------------------------------------------------------
// Gather: one wave per node, lane = 2 channels; h coef-premultiplied so the
// inner op is a plain add. 8/4/1 unroll cascade for load ILP.
// ---------------------------------------------------------------------------
__global__ void __launch_bounds__(256) gather_kernel(
    const int* __restrict__ offsets, const int* __restrict__ edata,
    const bf16* __restrict__ h,          // [3][N][C]
    const bf16* __restrict__ hs,         // [N][C]
    void* __restrict__ out,
    const int* __restrict__ flags)
{
    const int node = blockIdx.x * 4 + (threadIdx.x >> 6);
    if (node >= N_NODES) return;
    const int lane = threadIdx.x & 63;
    const int c = lane * 2;

    bf16x2 sv = *(const bf16x2*)(hs + (size_t)node * C + c);
    float a0 = (float)sv[0], a1 = (float)sv[1];

    const int s = offsets[node], e = offsets[node + 1];
    for (int base = s; base < e; base += 64) {
        int idx = base + lane;
        int ed_i = (idx < e) ? edata[idx] : 0;
        int cnt = e - base; if (cnt > 64) cnt = 64;
        int j = 0;
        for (; j + 8 <= cnt; j += 8) {
            float t0 = 0.f, t1 = 0.f;
            #pragma unroll
            for (int u = 0; u < 8; ++u) {
                int ed = __shfl(ed_i, j + u);
                bf16x2 v = *(const bf16x2*)(h + (size_t)(ed & 3) * (N_NODES * C)
                                              + (size_t)(ed >> 2) * C + c);
                t0 += (float)v[0];
                t1 += (float)v[1];
            }
            a0 += t0; a1 += t1;
        }
        for (; j + 4 <= cnt; j += 4) {
            int e0 = __shfl(ed_i, j);
            int e1 = __shfl(ed_i, j + 1);
            int e2 = __shfl(ed_i, j + 2);
            int e3 = __shfl(ed_i, j + 3);
            bf16x2 v0 = *(const bf16x2*)(h + (size_t)(e0 & 3) * (N_NODES * C) + (size_t)(e0 >> 2) * C + c);
            bf16x2 v1 = *(const bf16x2*)(h + (size_t)(e1 & 3) * (N_NODES * C) + (size_t)(e1 >> 2) * C + c);
            bf16x2 v2 = *(const bf16x2*)(h + (size_t)(e2 & 3) * (N_NODES * C) + (size_t)(e2 >> 2) * C + c);
            bf16x2 v3 = *(const bf16x2*)(h + (size_t)(e3 & 3) * (N_NODES * C) + (size_t)(e3 >> 2) * C + c);
            a0 += (float)v0[0] + (float)v1[0] + (float)v2[0] + (float)v3[0];
            a1 += (float)v0[1] + (float)v1[1] + (float)v2[1] + (float)v3[1];
        }
        for (; j < cnt; ++j) {
            int ed = __shfl(ed_i, j);
            bf16x2 v = *(const bf16x2*)(h + (size_t)(ed & 3) * (N_NODES * C) + (size_t)(ed >> 2) * C + c);
            a0 += (float)v[0];
            a1 += (float)v[1];
        }
    }

    if (flags[0]) {
        f32x2 o; o[0] = a0; o[1] = a1;
        *(f32x2*)((float*)out + (size_t)node * C + c) = o;
    } else {
        bf16x2 o; o[0] = (bf16)a0; o[1] = (bf16)a1;
        *(bf16x2*)((bf16*)out + (size_t)node * C + c) = o;
    }
}

// ---------------------------------------------------------------------------
extern "C" void kernel_launch(void* const* d_in, const int* in_sizes, int n_in,
                              void* d_out, int out_size, void* d_ws, size_t ws_size,
                              hipStream_t stream) {
    // 0 t | 1 node_embeddings [3,N,C] | 2 edge_index [2,E] | 3 edge_weights [E]
    // 4 loop_W1 5 loop_b1 6 loop_W2 7 loop_b2 | 8 rel_W1 9 rel_b1 10 rel_W2 11 rel_b2
    // 12 hh_W1 [2,C,C] 13 hh_b1 [2,C] 14 hh_W2 [2,C,C] 15 hh_b2 [2,C] | 16 hop_coef [3]
    const void* emb = d_in[1];
    const int*  ei  = (const int*)d_in[2];
    const int*  ew  = (const int*)d_in[3];

    // ws layout
    const size_t H_BYTES  = (size_t)3 * N_NODES * C * sizeof(bf16);   // 38.4 MB
    const size_t HS_BYTES = (size_t)N_NODES * C * sizeof(bf16);       // 12.8 MB
    const size_t PW_BYTES = (size_t)8 * 16384 * sizeof(bf16);         // 256 KB
    bf16*  h      = (bf16*)d_ws;
    bf16*  hs     = (bf16*)((char*)d_ws + H_BYTES);
    bf16*  pw     = (bf16*)((char*)d_ws + H_BYTES + HS_BYTES);
    float* cbias  = (float*)((char*)d_ws + H_BYTES + HS_BYTES + PW_BYTES);
    float* ccoef  = cbias + 1024;
    int*   flags  = (int*)(ccoef + 4);
    int*   deg    = flags + 16;
    int*   cursor = deg + N_NODES;
    int*   offsets= cursor + N_NODES;
    int*   btot   = offsets + N_NODES + 8;
    int*   bbase  = btot + 256;
    int*   edata  = bbase + 256;

    // pack slots: 0 rel_W1, 1 rel_W2, 2 hh_W1[0], 3 hh_W2[0], 4 hh_W1[1], 5 hh_W2[1], 6 loop_W1, 7 loop_W2
    PtrsV wptr;
    wptr.p[0] = d_in[8];   wptr.p[1] = d_in[10];
    wptr.p[2] = d_in[12];  wptr.p[3] = d_in[14];
    wptr.p[4] = d_in[12];  wptr.p[5] = d_in[14];   // +16384 elems inside pack
    wptr.p[6] = d_in[4];   wptr.p[7] = d_in[6];
    PtrsV bptr;
    bptr.p[0] = d_in[9];   bptr.p[1] = d_in[11];
    bptr.p[2] = d_in[13];  bptr.p[3] = d_in[15];
    bptr.p[4] = d_in[13];  bptr.p[5] = d_in[15];   // +128 inside pack
    bptr.p[6] = d_in[5];   bptr.p[7] = d_in[7];

    const int NBLK = (N_NODES + 255) / 256;   // 196

    detect_zero_kernel<<<1 + NBLK, 256, 0, stream>>>(
        (const unsigned short*)emb, (const unsigned short*)d_in[8],
        (const unsigned short*)d_in[9], (const unsigned short*)d_in[16],
        flags, deg);

    pack_kernel<<<517, 256, 0, stream>>>(wptr, bptr, d_in[16], flags, pw, cbias, ccoef);

    const int* erow = ei;
    const int* ecol = ei + N_EDGES;
    hist_kernel<<<(N_EDGES + 255) / 256, 256, 0, stream>>>(erow, deg);
    scanA_kernel<<<NBLK, 256, 0, stream>>>(deg, offsets, btot);
    scanB_kernel<<<1, 256, 0, stream>>>(btot, bbase, NBLK);
    scanC_kernel<<<NBLK, 256, 0, stream>>>(bbase, offsets, cursor);
    fill_kernel<<<(N_EDGES + 255) / 256, 256, 0, stream>>>(erow, ecol, ew, cursor, edata);

    // MLPs: 4 tasks x 3125 strips, one wave per (task, strip)
    mlp_kernel<<<(N_TASKS * GROUPS + 3) / 4, 256, 0, stream>>>(
        emb, pw, cbias, ccoef, flags, h, hs);

    gather_kernel<<<(N_NODES + 3) / 4, 256, 0, stream>>>(
        offsets, edata, h, hs, d_out, flags);
}

// Round 3
// 269.441 us; speedup vs baseline: 1.1026x; 1.1026x over previous
//
#include <hip/hip_runtime.h>

#define N_NODES 50000
#define N_EDGES 600000
#define C 128
#define STRIPS 3125          // N_NODES / 16
#define N_TASKS 4            // 0 rel(L2) 1 hh0(L1) 2 hh1(L0) 3 loop(L2)
#define MLP_BLOCKS 256       // R9: persistent-ish, 1 block/CU; task = blk&3
#define SLOT_STRIDE 512      // 64 block-slots/task * 8 waves

typedef __bf16 bf16;
typedef __attribute__((ext_vector_type(8))) __bf16 bf16x8;
typedef __attribute__((ext_vector_type(4))) __bf16 bf16x4;
typedef __attribute__((ext_vector_type(2))) __bf16 bf16x2;
typedef __attribute__((ext_vector_type(4))) float f32x4;
typedef __attribute__((ext_vector_type(2))) float f32x2;

struct PtrsV { const void* p[8]; };

// ---------------------------------------------------------------------------
// Dtype detection (verified R2-R6) + deg zeroing. flags 1 = fp32, 0 = bf16.
// ---------------------------------------------------------------------------
__device__ __forceinline__ int bf16_wild(unsigned short w) {
    int exp = (w >> 7) & 0xFF;
    int mant = w & 0x7F;
    if (exp == 0xFF) return 1;
    if (exp >= 133) return 1;                // |x| >= 64
    if (exp == 0) return mant != 0 ? 1 : 0;  // denormal
    if (exp <= 114) return 1;                // 0 < |x| < 2^-12
    return 0;
}

__global__ void __launch_bounds__(256) detect_zero_kernel(
    const unsigned short* __restrict__ emb,
    const unsigned short* __restrict__ w,
    const unsigned short* __restrict__ b,
    const unsigned short* __restrict__ hc,
    int* __restrict__ flags, int* __restrict__ deg)
{
    if (blockIdx.x == 0) {
        int lane = threadIdx.x;
        if (lane >= 64) return;
        int ce = 0, cw = 0, cb = 0, ch = 0;
        for (int j = 0; j < 4; ++j) {
            ce += bf16_wild(emb[lane * 4 + j]);
            cw += bf16_wild(w[lane * 4 + j]);
        }
        for (int j = 0; j < 2; ++j) cb += bf16_wild(b[lane * 2 + j]);
        if (lane < 3) ch = bf16_wild(hc[lane]);
        for (int off = 32; off > 0; off >>= 1) {
            ce += __shfl_down(ce, off);
            cw += __shfl_down(cw, off);
            cb += __shfl_down(cb, off);
            ch += __shfl_down(ch, off);
        }
        if (lane == 0) {
            int wf = (cw >= 16) ? 1 : 0;
            flags[0] = (ce >= 16) ? 1 : 0;
            flags[1] = wf;
            flags[2] = (cb >= 8) ? 1 : 0;
            flags[3] = (ch > 0) ? 1 : wf;
        }
    } else {
        int i = (blockIdx.x - 1) * 256 + threadIdx.x;
        if (i < N_NODES) deg[i] = 0;
    }
}

// ---------------------------------------------------------------------------
// Pack weights into MFMA B-fragment order (verified R2-R6).
// Frag index within matrix (as bf16x8): kk*512 + n0*64 + lane.
// Slots 4,5 are the second hh matrix (+16384 elems / +128 bias).
// ---------------------------------------------------------------------------
__global__ void __launch_bounds__(256) pack_kernel(
    PtrsV wmats, PtrsV bvecs, const void* hc_raw,
    const int* __restrict__ flags,
    bf16* __restrict__ pw, float* __restrict__ cbias, float* __restrict__ ccoef)
{
    int tid = blockIdx.x * 256 + threadIdx.x;
    int wf = flags[1], bfl = flags[2], hf = flags[3];
    if (tid < 8 * 16384) {
        int m    = tid >> 14;
        int r    = tid & 16383;
        int j    = r & 7;
        int lane = (r >> 3) & 63;
        int n0   = (r >> 9) & 7;
        int kk   = r >> 12;
        int k = kk * 32 + (lane >> 4) * 8 + j;
        int n = n0 * 16 + (lane & 15);
        int idx = k * C + n + ((m == 4 || m == 5) ? 16384 : 0);
        float v = wf ? ((const float*)wmats.p[m])[idx]
                     : (float)((const bf16*)wmats.p[m])[idx];
        pw[tid] = (bf16)v;
    } else if (tid < 8 * 16384 + 1024) {
        int j = tid - 8 * 16384;
        int m = j >> 7, n = j & 127;
        int idx = n + ((m == 4 || m == 5) ? 128 : 0);
        float v = bfl ? ((const float*)bvecs.p[m])[idx]
                      : (float)((const bf16*)bvecs.p[m])[idx];
        cbias[j] = v;
    } else if (tid < 8 * 16384 + 1024 + 3) {
        int i = tid - (8 * 16384 + 1024);
        float v = hf ? ((const float*)hc_raw)[i]
                     : (float)((const bf16*)hc_raw)[i];
        ccoef[i] = v;
    }
}

// ---------------------------------------------------------------------------
// MLP v7 (R9): R7/R8 showed occupancy is NOT the limiter (cap doubled,
// achieved stuck at ~35%, dur flat at 67us; MfmaUtil 7%). The stall is the
// per-n0 B-fragment chain: 4x1KB global loads -> vmcnt(0) -> 4 MFMA, 16x per
// strip, every load an L1-miss/L2-hit with contended latency. Fix: one task
// per block, 512 threads (8 waves), stage the task's 64KB of packed weights
// in LDS once, then each wave loops over strips reading B via conflict-free
// lane-linear ds_read_b128. A-loads for the next strip are issued before the
// current strip's GEMMs (software prefetch). LDS 64KB + 8*4.25KB = 100KB ->
// 1 block/CU, grid = 256 = 1/CU. MFMA/pack/transpose/store layouts unchanged.
// ---------------------------------------------------------------------------
__global__ __launch_bounds__(512, 2) void mlp_kernel(
    const void* __restrict__ emb_raw,    // [3][N][C] fp32 or bf16
    const bf16* __restrict__ pw,         // packed weights [8][16384]
    const float* __restrict__ cbias,     // [8][128]
    const float* __restrict__ ccoef,     // [3]
    const int* __restrict__ flags,
    bf16* __restrict__ h,                // [3][N][C], premultiplied by coef
    bf16* __restrict__ hs)               // [N][C] self term (loop MLP)
{
    __shared__ bf16 sW[32768];           // 64 KB: W1 then W2 fragments (this task)
    __shared__ bf16 sH[8][16][136];      // 34.8 KB: per-wave transpose buffer
    const int tid  = threadIdx.x;
    const int wave = tid >> 6, lane = tid & 63;
    const int task  = blockIdx.x & 3;
    const int bslot = blockIdx.x >> 2;          // 0..63
    const int lrow = lane & 15, lquad = lane >> 4;
    bf16 (*sh)[136] = sH[wave];

    const int m1_of[4] = {0, 2, 4, 6};
    const int ly_of[4] = {2, 1, 0, 2};
    const int m1 = m1_of[task];
    const float oscale = (task == 0) ? ccoef[0] : (task == 1) ? ccoef[1]
                       : (task == 2) ? ccoef[2] : 1.0f;
    bf16* outp = (task == 3) ? hs : (h + (size_t)task * N_NODES * C);
    const int emb_f32 = flags[0];
    const size_t lbase = (size_t)ly_of[task] * N_NODES * C;

    // ---- stage this task's weights into LDS (64 KB = 4096 x 16B) ----
    {
        const f32x4* src = (const f32x4*)(pw + (size_t)m1 * 16384);
        f32x4* dst = (f32x4*)sW;
        #pragma unroll
        for (int i = 0; i < 8; ++i)
            dst[i * 512 + tid] = src[i * 512 + tid];
    }
    __syncthreads();
    const bf16x8* w1v = (const bf16x8*)sW;      // frag (kk*512 + n0*64 + lane)
    const bf16x8* w2v = w1v + 2048;

    // ---- biases for this lane's columns ----
    float b1f[8], b2f[8];
    #pragma unroll
    for (int n0 = 0; n0 < 8; ++n0) {
        b1f[n0] = cbias[m1 * 128 + n0 * 16 + lrow];
        b2f[n0] = cbias[(m1 + 1) * 128 + n0 * 16 + lrow];
    }

    // ---- strip loop: slot-strided, A prefetched one strip ahead ----
    int s = bslot * 8 + wave;                   // 0..511 (< STRIPS, prologue safe)
    f32x4 u[8]; bf16x8 araw[4];

    // prologue: issue raw A loads for first strip
    {
        size_t xb = lbase + (size_t)(s * 16 + lrow) * C + lquad * 8;
        if (emb_f32) {
            const float* xf = (const float*)emb_raw + xb;
            #pragma unroll
            for (int kk = 0; kk < 4; ++kk) {
                u[kk * 2]     = *(const f32x4*)(xf + kk * 32);
                u[kk * 2 + 1] = *(const f32x4*)(xf + kk * 32 + 4);
            }
        } else {
            const bf16* x16 = (const bf16*)emb_raw + xb;
            #pragma unroll
            for (int kk = 0; kk < 4; ++kk)
                araw[kk] = *(const bf16x8*)(x16 + kk * 32);
        }
    }

    while (s < STRIPS) {
        const int snext = s + SLOT_STRIDE;

        // convert raw -> af (frees the raw buffers for the prefetch)
        bf16x8 af[4];
        if (emb_f32) {
            #pragma unroll
            for (int kk = 0; kk < 4; ++kk) {
                f32x4 u0 = u[kk * 2], u1 = u[kk * 2 + 1];
                bf16x8 v;
                v[0]=(bf16)u0[0]; v[1]=(bf16)u0[1]; v[2]=(bf16)u0[2]; v[3]=(bf16)u0[3];
                v[4]=(bf16)u1[0]; v[5]=(bf16)u1[1]; v[6]=(bf16)u1[2]; v[7]=(bf16)u1[3];
                af[kk] = v;
            }
        } else {
            #pragma unroll
            for (int kk = 0; kk < 4; ++kk) af[kk] = araw[kk];
        }

        // issue raw A loads for the NEXT strip (in flight during GEMMs)
        if (snext < STRIPS) {
            size_t xb = lbase + (size_t)(snext * 16 + lrow) * C + lquad * 8;
            if (emb_f32) {
                const float* xf = (const float*)emb_raw + xb;
                #pragma unroll
                for (int kk = 0; kk < 4; ++kk) {
                    u[kk * 2]     = *(const f32x4*)(xf + kk * 32);
                    u[kk * 2 + 1] = *(const f32x4*)(xf + kk * 32 + 4);
                }
            } else {
                const bf16* x16 = (const bf16*)emb_raw + xb;
                #pragma unroll
                for (int kk = 0; kk < 4; ++kk)
                    araw[kk] = *(const bf16x8*)(x16 + kk * 32);
            }
        }

        // ---- GEMM1: hidden = relu(X @ W1 + b1) -> sh, B from LDS ----
        #pragma unroll
        for (int n0 = 0; n0 < 8; ++n0) {
            bf16x8 bv0 = w1v[0 * 512 + n0 * 64 + lane];
            bf16x8 bv1 = w1v[1 * 512 + n0 * 64 + lane];
            bf16x8 bv2 = w1v[2 * 512 + n0 * 64 + lane];
            bf16x8 bv3 = w1v[3 * 512 + n0 * 64 + lane];
            int n = n0 * 16 + lrow;
            float bias = b1f[n0];
            f32x4 a4 = {0.f, 0.f, 0.f, 0.f};
            a4 = __builtin_amdgcn_mfma_f32_16x16x32_bf16(af[0], bv0, a4, 0, 0, 0);
            a4 = __builtin_amdgcn_mfma_f32_16x16x32_bf16(af[1], bv1, a4, 0, 0, 0);
            a4 = __builtin_amdgcn_mfma_f32_16x16x32_bf16(af[2], bv2, a4, 0, 0, 0);
            a4 = __builtin_amdgcn_mfma_f32_16x16x32_bf16(af[3], bv3, a4, 0, 0, 0);
            #pragma unroll
            for (int r = 0; r < 4; ++r) {
                float v = a4[r] + bias;
                v = v > 0.f ? v : 0.f;
                sh[lquad * 4 + r][n] = (bf16)v;
            }
        }

        // ---- read GEMM2 A-frags (in-wave LDS RAW, compiler-ordered) ----
        bf16x8 ah[4];
        #pragma unroll
        for (int kk = 0; kk < 4; ++kk)
            ah[kk] = *(const bf16x8*)(&sh[lrow][kk * 32 + lquad * 8]);

        // ---- GEMM2: out = oscale*(hidden @ W2 + b2) -> sh ----
        #pragma unroll
        for (int n0 = 0; n0 < 8; ++n0) {
            bf16x8 bv0 = w2v[0 * 512 + n0 * 64 + lane];
            bf16x8 bv1 = w2v[1 * 512 + n0 * 64 + lane];
            bf16x8 bv2 = w2v[2 * 512 + n0 * 64 + lane];
            bf16x8 bv3 = w2v[3 * 512 + n0 * 64 + lane];
            int n = n0 * 16 + lrow;
            float bias = b2f[n0];
            f32x4 a4 = {0.f, 0.f, 0.f, 0.f};
            a4 = __builtin_amdgcn_mfma_f32_16x16x32_bf16(ah[0], bv0, a4, 0, 0, 0);
            a4 = __builtin_amdgcn_mfma_f32_16x16x32_bf16(ah[1], bv1, a4, 0, 0, 0);
            a4 = __builtin_amdgcn_mfma_f32_16x16x32_bf16(ah[2], bv2, a4, 0, 0, 0);
            a4 = __builtin_amdgcn_mfma_f32_16x16x32_bf16(ah[3], bv3, a4, 0, 0, 0);
            #pragma unroll
            for (int r = 0; r < 4; ++r)
                sh[lquad * 4 + r][n] = (bf16)((a4[r] + bias) * oscale);
        }

        // ---- coalesced store of 16 rows ----
        {
            int row = lane >> 2;
            int cs  = (lane & 3) * 32;
            bf16* dst = outp + (size_t)(s * 16) * C;
            #pragma unroll
            for (int j = 0; j < 4; ++j) {
                bf16x8 v = *(const bf16x8*)(&sh[row][cs + j * 8]);
                *(bf16x8*)(dst + (size_t)row * C + cs + j * 8) = v;
            }
        }

        s = snext;
    }
}

// ---------------------------------------------------------------------------
// CSR build: histogram, 3-phase scan, bucket fill (verified R5/R6).
// ---------------------------------------------------------------------------
__global__ void __launch_bounds__(256) hist_kernel(
    const int* __restrict__ erow, int* __restrict__ deg)
{
    int e = blockIdx.x * 256 + threadIdx.x;
    if (e >= N_EDGES) return;
    atomicAdd(&deg[erow[e]], 1);
}

__device__ __forceinline__ int wave_incl_scan(int v, int lane) {
    int x = v;
    #pragma unroll
    for (int d = 1; d < 64; d <<= 1) {
        int t = __shfl_up(x, d);
        if (lane >= d) x += t;
    }
    return x;
}

__global__ void __launch_bounds__(256) scanA_kernel(
    const int* __restrict__ deg, int* __restrict__ offsets, int* __restrict__ btot)
{
    __shared__ int swave[4];
    int b = blockIdx.x, tid = threadIdx.x;
    int i = b * 256 + tid;
    int lane = tid & 63, wv = tid >> 6;
    int v = (i < N_NODES) ? deg[i] : 0;
    int x = wave_incl_scan(v, lane);
    if (lane == 63) swave[wv] = x;
    __syncthreads();
    int w0 = swave[0], w1 = swave[1], w2 = swave[2], w3 = swave[3];
    int wp = (wv > 0 ? w0 : 0) + (wv > 1 ? w1 : 0) + (wv > 2 ? w2 : 0);
    if (i < N_NODES) offsets[i] = wp + x - v;
    if (tid == 0) btot[b] = w0 + w1 + w2 + w3;
}

__global__ void __launch_bounds__(256) scanB_kernel(
    const int* __restrict__ btot, int* __restrict__ bbase, int nblk)
{
    __shared__ int swave[4];
    int tid = threadIdx.x;
    int lane = tid & 63, wv = tid >> 6;
    int v = (tid < nblk) ? btot[tid] : 0;
    int x = wave_incl_scan(v, lane);
    if (lane == 63) swave[wv] = x;
    __syncthreads();
    int w0 = swave[0], w1 = swave[1], w2 = swave[2], w3 = swave[3];
    int wp = (wv > 0 ? w0 : 0) + (wv > 1 ? w1 : 0) + (wv > 2 ? w2 : 0);
    if (tid < nblk) bbase[tid] = wp + x - v;
}

__global__ void __launch_bounds__(256) scanC_kernel(
    const int* __restrict__ bbase, int* __restrict__ offsets, int* __restrict__ cursor)
{
    int i = blockIdx.x * 256 + threadIdx.x;
    if (i < N_NODES) {
        int o = offsets[i] + bbase[blockIdx.x];
        offsets[i] = o;
        cursor[i] = o;
    }
    if (i == 0) offsets[N_NODES] = N_EDGES;
}

__global__ void __launch_bounds__(256) fill_kernel(
    const int* __restrict__ erow, const int* __restrict__ ecol,
    const int* __restrict__ ew,
    int* __restrict__ cursor, int* __restrict__ edata)
{
    int e = blockIdx.x * 256 + threadIdx.x;
    if (e >= N_EDGES) return;
    int dst = erow[e];
    int pos = atomicAdd(&cursor[dst], 1);
    edata[pos] = (ecol[e] << 2) | (ew[e] - 1);
}

// ---------------------------------------------------------------------------
// Gather: one wave per node, lane = 2 channels; h coef-premultiplied so the
// inner op is a plain add. 8/4/1 unroll cascade for load ILP.
// ---------------------------------------------------------------------------
__global__ void __launch_bounds__(256) gather_kernel(
    const int* __restrict__ offsets, const int* __restrict__ edata,
    const bf16* __restrict__ h,          // [3][N][C]
    const bf16* __restrict__ hs,         // [N][C]
    void* __restrict__ out,
    const int* __restrict__ flags)
{
    const int node = blockIdx.x * 4 + (threadIdx.x >> 6);
    if (node >= N_NODES) return;
    const int lane = threadIdx.x & 63;
    const int c = lane * 2;

    bf16x2 sv = *(const bf16x2*)(hs + (size_t)node * C + c);
    float a0 = (float)sv[0], a1 = (float)sv[1];

    const int s = offsets[node], e = offsets[node + 1];
    for (int base = s; base < e; base += 64) {
        int idx = base + lane;
        int ed_i = (idx < e) ? edata[idx] : 0;
        int cnt = e - base; if (cnt > 64) cnt = 64;
        int j = 0;
        for (; j + 8 <= cnt; j += 8) {
            float t0 = 0.f, t1 = 0.f;
            #pragma unroll
            for (int u = 0; u < 8; ++u) {
                int ed = __shfl(ed_i, j + u);
                bf16x2 v = *(const bf16x2*)(h + (size_t)(ed & 3) * (N_NODES * C)
                                              + (size_t)(ed >> 2) * C + c);
                t0 += (float)v[0];
                t1 += (float)v[1];
            }
            a0 += t0; a1 += t1;
        }
        for (; j + 4 <= cnt; j += 4) {
            int e0 = __shfl(ed_i, j);
            int e1 = __shfl(ed_i, j + 1);
            int e2 = __shfl(ed_i, j + 2);
            int e3 = __shfl(ed_i, j + 3);
            bf16x2 v0 = *(const bf16x2*)(h + (size_t)(e0 & 3) * (N_NODES * C) + (size_t)(e0 >> 2) * C + c);
            bf16x2 v1 = *(const bf16x2*)(h + (size_t)(e1 & 3) * (N_NODES * C) + (size_t)(e1 >> 2) * C + c);
            bf16x2 v2 = *(const bf16x2*)(h + (size_t)(e2 & 3) * (N_NODES * C) + (size_t)(e2 >> 2) * C + c);
            bf16x2 v3 = *(const bf16x2*)(h + (size_t)(e3 & 3) * (N_NODES * C) + (size_t)(e3 >> 2) * C + c);
            a0 += (float)v0[0] + (float)v1[0] + (float)v2[0] + (float)v3[0];
            a1 += (float)v0[1] + (float)v1[1] + (float)v2[1] + (float)v3[1];
        }
        for (; j < cnt; ++j) {
            int ed = __shfl(ed_i, j);
            bf16x2 v = *(const bf16x2*)(h + (size_t)(ed & 3) * (N_NODES * C) + (size_t)(ed >> 2) * C + c);
            a0 += (float)v[0];
            a1 += (float)v[1];
        }
    }

    if (flags[0]) {
        f32x2 o; o[0] = a0; o[1] = a1;
        *(f32x2*)((float*)out + (size_t)node * C + c) = o;
    } else {
        bf16x2 o; o[0] = (bf16)a0; o[1] = (bf16)a1;
        *(bf16x2*)((bf16*)out + (size_t)node * C + c) = o;
    }
}

// ---------------------------------------------------------------------------
extern "C" void kernel_launch(void* const* d_in, const int* in_sizes, int n_in,
                              void* d_out, int out_size, void* d_ws, size_t ws_size,
                              hipStream_t stream) {
    // 0 t | 1 node_embeddings [3,N,C] | 2 edge_index [2,E] | 3 edge_weights [E]
    // 4 loop_W1 5 loop_b1 6 loop_W2 7 loop_b2 | 8 rel_W1 9 rel_b1 10 rel_W2 11 rel_b2
    // 12 hh_W1 [2,C,C] 13 hh_b1 [2,C] 14 hh_W2 [2,C,C] 15 hh_b2 [2,C] | 16 hop_coef [3]
    const void* emb = d_in[1];
    const int*  ei  = (const int*)d_in[2];
    const int*  ew  = (const int*)d_in[3];

    // ws layout
    const size_t H_BYTES  = (size_t)3 * N_NODES * C * sizeof(bf16);   // 38.4 MB
    const size_t HS_BYTES = (size_t)N_NODES * C * sizeof(bf16);       // 12.8 MB
    const size_t PW_BYTES = (size_t)8 * 16384 * sizeof(bf16);         // 256 KB
    bf16*  h      = (bf16*)d_ws;
    bf16*  hs     = (bf16*)((char*)d_ws + H_BYTES);
    bf16*  pw     = (bf16*)((char*)d_ws + H_BYTES + HS_BYTES);
    float* cbias  = (float*)((char*)d_ws + H_BYTES + HS_BYTES + PW_BYTES);
    float* ccoef  = cbias + 1024;
    int*   flags  = (int*)(ccoef + 4);
    int*   deg    = flags + 16;
    int*   cursor = deg + N_NODES;
    int*   offsets= cursor + N_NODES;
    int*   btot   = offsets + N_NODES + 8;
    int*   bbase  = btot + 256;
    int*   edata  = bbase + 256;

    // pack slots: 0 rel_W1, 1 rel_W2, 2 hh_W1[0], 3 hh_W2[0], 4 hh_W1[1], 5 hh_W2[1], 6 loop_W1, 7 loop_W2
    PtrsV wptr;
    wptr.p[0] = d_in[8];   wptr.p[1] = d_in[10];
    wptr.p[2] = d_in[12];  wptr.p[3] = d_in[14];
    wptr.p[4] = d_in[12];  wptr.p[5] = d_in[14];   // +16384 elems inside pack
    wptr.p[6] = d_in[4];   wptr.p[7] = d_in[6];
    PtrsV bptr;
    bptr.p[0] = d_in[9];   bptr.p[1] = d_in[11];
    bptr.p[2] = d_in[13];  bptr.p[3] = d_in[15];
    bptr.p[4] = d_in[13];  bptr.p[5] = d_in[15];   // +128 inside pack
    bptr.p[6] = d_in[5];   bptr.p[7] = d_in[7];

    const int NBLK = (N_NODES + 255) / 256;   // 196

    detect_zero_kernel<<<1 + NBLK, 256, 0, stream>>>(
        (const unsigned short*)emb, (const unsigned short*)d_in[8],
        (const unsigned short*)d_in[9], (const unsigned short*)d_in[16],
        flags, deg);

    pack_kernel<<<517, 256, 0, stream>>>(wptr, bptr, d_in[16], flags, pw, cbias, ccoef);

    const int* erow = ei;
    const int* ecol = ei + N_EDGES;
    hist_kernel<<<(N_EDGES + 255) / 256, 256, 0, stream>>>(erow, deg);
    scanA_kernel<<<NBLK, 256, 0, stream>>>(deg, offsets, btot);
    scanB_kernel<<<1, 256, 0, stream>>>(btot, bbase, NBLK);
    scanC_kernel<<<NBLK, 256, 0, stream>>>(bbase, offsets, cursor);
    fill_kernel<<<(N_EDGES + 255) / 256, 256, 0, stream>>>(erow, ecol, ew, cursor, edata);

    // MLPs: 256 blocks (1/CU), task = blk&3, 8 waves loop over strips
    mlp_kernel<<<MLP_BLOCKS, 512, 0, stream>>>(
        emb, pw, cbias, ccoef, flags, h, hs);

    gather_kernel<<<(N_NODES + 3) / 4, 256, 0, stream>>>(
        offsets, edata, h, hs, d_out, flags);
}

// Round 4
// 269.237 us; speedup vs baseline: 1.1034x; 1.0008x over previous
//
#include <hip/hip_runtime.h>

#define N_NODES 50000
#define N_EDGES 600000
#define C 128
#define STRIPS 3125          // N_NODES / 16
#define N_TASKS 4            // 0 rel(L2) 1 hh0(L1) 2 hh1(L0) 3 loop(L2)
#define MLP_BLOCKS 256       // 1 block/CU; task = blk&3
// R10 schedule: 512 waves/task. Items per wave: 3 pairs (strips 0..3071 as
// 1536 pairs, rounds r=0..2 at pair index widx+512r) + 1 single for widx<53
// (strips 3072..3124). Balanced: tail is a half-item for 53/512 waves.

typedef __bf16 bf16;
typedef __attribute__((ext_vector_type(8))) __bf16 bf16x8;
typedef __attribute__((ext_vector_type(4))) __bf16 bf16x4;
typedef __attribute__((ext_vector_type(2))) __bf16 bf16x2;
typedef __attribute__((ext_vector_type(4))) float f32x4;
typedef __attribute__((ext_vector_type(2))) float f32x2;

struct PtrsV { const void* p[8]; };

// ---------------------------------------------------------------------------
// Dtype detection (verified R2-R6) + deg zeroing. flags 1 = fp32, 0 = bf16.
// ---------------------------------------------------------------------------
__device__ __forceinline__ int bf16_wild(unsigned short w) {
    int exp = (w >> 7) & 0xFF;
    int mant = w & 0x7F;
    if (exp == 0xFF) return 1;
    if (exp >= 133) return 1;                // |x| >= 64
    if (exp == 0) return mant != 0 ? 1 : 0;  // denormal
    if (exp <= 114) return 1;                // 0 < |x| < 2^-12
    return 0;
}

__global__ void __launch_bounds__(256) detect_zero_kernel(
    const unsigned short* __restrict__ emb,
    const unsigned short* __restrict__ w,
    const unsigned short* __restrict__ b,
    const unsigned short* __restrict__ hc,
    int* __restrict__ flags, int* __restrict__ deg)
{
    if (blockIdx.x == 0) {
        int lane = threadIdx.x;
        if (lane >= 64) return;
        int ce = 0, cw = 0, cb = 0, ch = 0;
        for (int j = 0; j < 4; ++j) {
            ce += bf16_wild(emb[lane * 4 + j]);
            cw += bf16_wild(w[lane * 4 + j]);
        }
        for (int j = 0; j < 2; ++j) cb += bf16_wild(b[lane * 2 + j]);
        if (lane < 3) ch = bf16_wild(hc[lane]);
        for (int off = 32; off > 0; off >>= 1) {
            ce += __shfl_down(ce, off);
            cw += __shfl_down(cw, off);
            cb += __shfl_down(cb, off);
            ch += __shfl_down(ch, off);
        }
        if (lane == 0) {
            int wf = (cw >= 16) ? 1 : 0;
            flags[0] = (ce >= 16) ? 1 : 0;
            flags[1] = wf;
            flags[2] = (cb >= 8) ? 1 : 0;
            flags[3] = (ch > 0) ? 1 : wf;
        }
    } else {
        int i = (blockIdx.x - 1) * 256 + threadIdx.x;
        if (i < N_NODES) deg[i] = 0;
    }
}

// ---------------------------------------------------------------------------
// Pack weights into MFMA B-fragment order (verified R2-R6).
// Frag index within matrix (as bf16x8): kk*512 + n0*64 + lane.
// Slots 4,5 are the second hh matrix (+16384 elems / +128 bias).
// ---------------------------------------------------------------------------
__global__ void __launch_bounds__(256) pack_kernel(
    PtrsV wmats, PtrsV bvecs, const void* hc_raw,
    const int* __restrict__ flags,
    bf16* __restrict__ pw, float* __restrict__ cbias, float* __restrict__ ccoef)
{
    int tid = blockIdx.x * 256 + threadIdx.x;
    int wf = flags[1], bfl = flags[2], hf = flags[3];
    if (tid < 8 * 16384) {
        int m    = tid >> 14;
        int r    = tid & 16383;
        int j    = r & 7;
        int lane = (r >> 3) & 63;
        int n0   = (r >> 9) & 7;
        int kk   = r >> 12;
        int k = kk * 32 + (lane >> 4) * 8 + j;
        int n = n0 * 16 + (lane & 15);
        int idx = k * C + n + ((m == 4 || m == 5) ? 16384 : 0);
        float v = wf ? ((const float*)wmats.p[m])[idx]
                     : (float)((const bf16*)wmats.p[m])[idx];
        pw[tid] = (bf16)v;
    } else if (tid < 8 * 16384 + 1024) {
        int j = tid - 8 * 16384;
        int m = j >> 7, n = j & 127;
        int idx = n + ((m == 4 || m == 5) ? 128 : 0);
        float v = bfl ? ((const float*)bvecs.p[m])[idx]
                      : (float)((const bf16*)bvecs.p[m])[idx];
        cbias[j] = v;
    } else if (tid < 8 * 16384 + 1024 + 3) {
        int i = tid - (8 * 16384 + 1024);
        float v = hf ? ((const float*)hc_raw)[i]
                     : (float)((const bf16*)hc_raw)[i];
        ccoef[i] = v;
    }
}

// ---------------------------------------------------------------------------
// MLP v8 (R10): R9 (LDS-staged B, 1 strip/iter) landed 46us; model says the
// dominant term is now the LDS pipe: each wave re-reads the full 64KB weight
// set per strip (512KB/CU per strip-round ~ 55% LDS-busy) serialized on
// ds_read->MFMA chains at 2 waves/SIMD. Fix: 2 strips per iteration -- each
// B fragment feeds 2 MFMAs (B ds_read traffic per node halves, MFMA ILP
// doubles). Compute body = R7's verified 2-strip code with B from LDS.
// LDS 64KB weights + 8*8.5KB sH = 132KB, 1 block/CU (unchanged cap).
// Schedule balanced: 3 exact pair-rounds + 53-wave single-strip tail.
// ---------------------------------------------------------------------------
__global__ __launch_bounds__(512, 2) void mlp_kernel(
    const void* __restrict__ emb_raw,    // [3][N][C] fp32 or bf16
    const bf16* __restrict__ pw,         // packed weights [8][16384]
    const float* __restrict__ cbias,     // [8][128]
    const float* __restrict__ ccoef,     // [3]
    const int* __restrict__ flags,
    bf16* __restrict__ h,                // [3][N][C], premultiplied by coef
    bf16* __restrict__ hs)               // [N][C] self term (loop MLP)
{
    __shared__ bf16 sW[32768];           // 64 KB: W1 then W2 fragments (this task)
    __shared__ bf16 sH[8][32][136];      // 68 KB: per-wave 2-strip transpose buf
    const int tid  = threadIdx.x;
    const int wave = tid >> 6, lane = tid & 63;
    const int task  = blockIdx.x & 3;
    const int bslot = blockIdx.x >> 2;          // 0..63
    const int widx  = bslot * 8 + wave;         // 0..511
    const int lrow = lane & 15, lquad = lane >> 4;
    bf16 (*sh)[136] = sH[wave];

    const int m1_of[4] = {0, 2, 4, 6};
    const int ly_of[4] = {2, 1, 0, 2};
    const int m1 = m1_of[task];
    const float oscale = (task == 0) ? ccoef[0] : (task == 1) ? ccoef[1]
                       : (task == 2) ? ccoef[2] : 1.0f;
    bf16* outp = (task == 3) ? hs : (h + (size_t)task * N_NODES * C);
    const int emb_f32 = flags[0];
    const size_t lbase = (size_t)ly_of[task] * N_NODES * C;

    // ---- stage this task's weights into LDS (64 KB = 4096 x 16B) ----
    {
        const f32x4* src = (const f32x4*)(pw + (size_t)m1 * 16384);
        f32x4* dst = (f32x4*)sW;
        #pragma unroll
        for (int i = 0; i < 8; ++i)
            dst[i * 512 + tid] = src[i * 512 + tid];
    }
    __syncthreads();
    const bf16x8* w1v = (const bf16x8*)sW;      // frag (kk*512 + n0*64 + lane)
    const bf16x8* w2v = w1v + 2048;

    // ---- biases for this lane's columns ----
    float b1f[8], b2f[8];
    #pragma unroll
    for (int n0 = 0; n0 < 8; ++n0) {
        b1f[n0] = cbias[m1 * 128 + n0 * 16 + lrow];
        b2f[n0] = cbias[(m1 + 1) * 128 + n0 * 16 + lrow];
    }

    const int nitems = 3 + (widx < 53 ? 1 : 0);

    // prefetch buffers for one item (up to 2 strips)
    f32x4 u[16]; bf16x8 araw[8];

    // issue raw A loads for item (s0v, pair if v2v)
    #define LOADA(s0v, v2v) do {                                              \
        _Pragma("unroll")                                                     \
        for (int i2 = 0; i2 < 2; ++i2) {                                      \
            if (i2 == 0 || (v2v)) {                                           \
                size_t xb = lbase + (size_t)(((s0v) + i2) * 16 + lrow) * C    \
                            + lquad * 8;                                      \
                if (emb_f32) {                                                \
                    const float* xf = (const float*)emb_raw + xb;             \
                    _Pragma("unroll")                                         \
                    for (int kk = 0; kk < 4; ++kk) {                          \
                        u[i2 * 8 + kk * 2]     = *(const f32x4*)(xf + kk*32); \
                        u[i2 * 8 + kk * 2 + 1] = *(const f32x4*)(xf + kk*32 + 4); \
                    }                                                         \
                } else {                                                      \
                    const bf16* x16 = (const bf16*)emb_raw + xb;              \
                    _Pragma("unroll")                                         \
                    for (int kk = 0; kk < 4; ++kk)                            \
                        araw[i2 * 4 + kk] = *(const bf16x8*)(x16 + kk * 32);  \
                }                                                             \
            }                                                                 \
        }                                                                     \
    } while (0)

    int ns0 = 2 * widx, nv2 = 1;     // item 0: pair (strips 2w, 2w+1)
    LOADA(ns0, nv2);

    for (int it = 0; it < nitems; ++it) {
        const int cs0 = ns0, cv2 = nv2;
        const int have_next = (it + 1 < nitems);

        // convert current prefetch -> af (frees buffers for next prefetch)
        bf16x8 af[2][4];
        #pragma unroll
        for (int i2 = 0; i2 < 2; ++i2) {
            if (i2 == 0 || cv2) {
                if (emb_f32) {
                    #pragma unroll
                    for (int kk = 0; kk < 4; ++kk) {
                        f32x4 u0 = u[i2 * 8 + kk * 2], u1 = u[i2 * 8 + kk * 2 + 1];
                        bf16x8 v;
                        v[0]=(bf16)u0[0]; v[1]=(bf16)u0[1]; v[2]=(bf16)u0[2]; v[3]=(bf16)u0[3];
                        v[4]=(bf16)u1[0]; v[5]=(bf16)u1[1]; v[6]=(bf16)u1[2]; v[7]=(bf16)u1[3];
                        af[i2][kk] = v;
                    }
                } else {
                    #pragma unroll
                    for (int kk = 0; kk < 4; ++kk) af[i2][kk] = araw[i2 * 4 + kk];
                }
            }
        }

        // issue raw A loads for the NEXT item (in flight during GEMMs)
        if (have_next) {
            ns0 = (it + 1 < 3) ? 2 * (widx + (it + 1) * 512) : 3072 + widx;
            nv2 = (it + 1 < 3) ? 1 : 0;
            LOADA(ns0, nv2);
        }

        // ---- GEMM1: hidden = relu(X @ W1 + b1) -> sh, B from LDS ----
        #pragma unroll
        for (int n0 = 0; n0 < 8; ++n0) {
            bf16x8 bv0 = w1v[0 * 512 + n0 * 64 + lane];
            bf16x8 bv1 = w1v[1 * 512 + n0 * 64 + lane];
            bf16x8 bv2 = w1v[2 * 512 + n0 * 64 + lane];
            bf16x8 bv3 = w1v[3 * 512 + n0 * 64 + lane];
            int n = n0 * 16 + lrow;
            float bias = b1f[n0];
            #pragma unroll
            for (int i2 = 0; i2 < 2; ++i2) {
                if (i2 == 0 || cv2) {
                    f32x4 a4 = {0.f, 0.f, 0.f, 0.f};
                    a4 = __builtin_amdgcn_mfma_f32_16x16x32_bf16(af[i2][0], bv0, a4, 0, 0, 0);
                    a4 = __builtin_amdgcn_mfma_f32_16x16x32_bf16(af[i2][1], bv1, a4, 0, 0, 0);
                    a4 = __builtin_amdgcn_mfma_f32_16x16x32_bf16(af[i2][2], bv2, a4, 0, 0, 0);
                    a4 = __builtin_amdgcn_mfma_f32_16x16x32_bf16(af[i2][3], bv3, a4, 0, 0, 0);
                    #pragma unroll
                    for (int r = 0; r < 4; ++r) {
                        float v = a4[r] + bias;
                        v = v > 0.f ? v : 0.f;
                        sh[i2 * 16 + lquad * 4 + r][n] = (bf16)v;
                    }
                }
            }
        }

        // ---- read GEMM2 A-frags (in-wave LDS RAW, compiler-ordered) ----
        bf16x8 ah[2][4];
        #pragma unroll
        for (int kk = 0; kk < 4; ++kk)
            ah[0][kk] = *(const bf16x8*)(&sh[lrow][kk * 32 + lquad * 8]);
        if (cv2) {
            #pragma unroll
            for (int kk = 0; kk < 4; ++kk)
                ah[1][kk] = *(const bf16x8*)(&sh[16 + lrow][kk * 32 + lquad * 8]);
        }

        // ---- GEMM2: out = oscale*(hidden @ W2 + b2) -> sh ----
        #pragma unroll
        for (int n0 = 0; n0 < 8; ++n0) {
            bf16x8 bv0 = w2v[0 * 512 + n0 * 64 + lane];
            bf16x8 bv1 = w2v[1 * 512 + n0 * 64 + lane];
            bf16x8 bv2 = w2v[2 * 512 + n0 * 64 + lane];
            bf16x8 bv3 = w2v[3 * 512 + n0 * 64 + lane];
            int n = n0 * 16 + lrow;
            float bias = b2f[n0];
            #pragma unroll
            for (int i2 = 0; i2 < 2; ++i2) {
                if (i2 == 0 || cv2) {
                    f32x4 a4 = {0.f, 0.f, 0.f, 0.f};
                    a4 = __builtin_amdgcn_mfma_f32_16x16x32_bf16(ah[i2][0], bv0, a4, 0, 0, 0);
                    a4 = __builtin_amdgcn_mfma_f32_16x16x32_bf16(ah[i2][1], bv1, a4, 0, 0, 0);
                    a4 = __builtin_amdgcn_mfma_f32_16x16x32_bf16(ah[i2][2], bv2, a4, 0, 0, 0);
                    a4 = __builtin_amdgcn_mfma_f32_16x16x32_bf16(ah[i2][3], bv3, a4, 0, 0, 0);
                    #pragma unroll
                    for (int r = 0; r < 4; ++r)
                        sh[i2 * 16 + lquad * 4 + r][n] = (bf16)((a4[r] + bias) * oscale);
                }
            }
        }

        // ---- coalesced store of 16 rows per valid strip ----
        {
            int row = lane >> 2;
            int cs  = (lane & 3) * 32;
            #pragma unroll
            for (int i2 = 0; i2 < 2; ++i2) {
                if (i2 == 0 || cv2) {
                    bf16* dst = outp + (size_t)((cs0 + i2) * 16) * C;
                    #pragma unroll
                    for (int j = 0; j < 4; ++j) {
                        bf16x8 v = *(const bf16x8*)(&sh[i2 * 16 + row][cs + j * 8]);
                        *(bf16x8*)(dst + (size_t)row * C + cs + j * 8) = v;
                    }
                }
            }
        }
    }
    #undef LOADA
}

// ---------------------------------------------------------------------------
// CSR build: histogram, 3-phase scan, bucket fill (verified R5/R6).
// ---------------------------------------------------------------------------
__global__ void __launch_bounds__(256) hist_kernel(
    const int* __restrict__ erow, int* __restrict__ deg)
{
    int e = blockIdx.x * 256 + threadIdx.x;
    if (e >= N_EDGES) return;
    atomicAdd(&deg[erow[e]], 1);
}

__device__ __forceinline__ int wave_incl_scan(int v, int lane) {
    int x = v;
    #pragma unroll
    for (int d = 1; d < 64; d <<= 1) {
        int t = __shfl_up(x, d);
        if (lane >= d) x += t;
    }
    return x;
}

__global__ void __launch_bounds__(256) scanA_kernel(
    const int* __restrict__ deg, int* __restrict__ offsets, int* __restrict__ btot)
{
    __shared__ int swave[4];
    int b = blockIdx.x, tid = threadIdx.x;
    int i = b * 256 + tid;
    int lane = tid & 63, wv = tid >> 6;
    int v = (i < N_NODES) ? deg[i] : 0;
    int x = wave_incl_scan(v, lane);
    if (lane == 63) swave[wv] = x;
    __syncthreads();
    int w0 = swave[0], w1 = swave[1], w2 = swave[2], w3 = swave[3];
    int wp = (wv > 0 ? w0 : 0) + (wv > 1 ? w1 : 0) + (wv > 2 ? w2 : 0);
    if (i < N_NODES) offsets[i] = wp + x - v;
    if (tid == 0) btot[b] = w0 + w1 + w2 + w3;
}

__global__ void __launch_bounds__(256) scanB_kernel(
    const int* __restrict__ btot, int* __restrict__ bbase, int nblk)
{
    __shared__ int swave[4];
    int tid = threadIdx.x;
    int lane = tid & 63, wv = tid >> 6;
    int v = (tid < nblk) ? btot[tid] : 0;
    int x = wave_incl_scan(v, lane);
    if (lane == 63) swave[wv] = x;
    __syncthreads();
    int w0 = swave[0], w1 = swave[1], w2 = swave[2], w3 = swave[3];
    int wp = (wv > 0 ? w0 : 0) + (wv > 1 ? w1 : 0) + (wv > 2 ? w2 : 0);
    if (tid < nblk) bbase[tid] = wp + x - v;
}

__global__ void __launch_bounds__(256) scanC_kernel(
    const int* __restrict__ bbase, int* __restrict__ offsets, int* __restrict__ cursor)
{
    int i = blockIdx.x * 256 + threadIdx.x;
    if (i < N_NODES) {
        int o = offsets[i] + bbase[blockIdx.x];
        offsets[i] = o;
        cursor[i] = o;
    }
    if (i == 0) offsets[N_NODES] = N_EDGES;
}

__global__ void __launch_bounds__(256) fill_kernel(
    const int* __restrict__ erow, const int* __restrict__ ecol,
    const int* __restrict__ ew,
    int* __restrict__ cursor, int* __restrict__ edata)
{
    int e = blockIdx.x * 256 + threadIdx.x;
    if (e >= N_EDGES) return;
    int dst = erow[e];
    int pos = atomicAdd(&cursor[dst], 1);
    edata[pos] = (ecol[e] << 2) | (ew[e] - 1);
}

// ---------------------------------------------------------------------------
// Gather: one wave per node, lane = 2 channels; h coef-premultiplied so the
// inner op is a plain add. 8/4/1 unroll cascade for load ILP.
// ---------------------------------------------------------------------------
__global__ void __launch_bounds__(256) gather_kernel(
    const int* __restrict__ offsets, const int* __restrict__ edata,
    const bf16* __restrict__ h,          // [3][N][C]
    const bf16* __restrict__ hs,         // [N][C]
    void* __restrict__ out,
    const int* __restrict__ flags)
{
    const int node = blockIdx.x * 4 + (threadIdx.x >> 6);
    if (node >= N_NODES) return;
    const int lane = threadIdx.x & 63;
    const int c = lane * 2;

    bf16x2 sv = *(const bf16x2*)(hs + (size_t)node * C + c);
    float a0 = (float)sv[0], a1 = (float)sv[1];

    const int s = offsets[node], e = offsets[node + 1];
    for (int base = s; base < e; base += 64) {
        int idx = base + lane;
        int ed_i = (idx < e) ? edata[idx] : 0;
        int cnt = e - base; if (cnt > 64) cnt = 64;
        int j = 0;
        for (; j + 8 <= cnt; j += 8) {
            float t0 = 0.f, t1 = 0.f;
            #pragma unroll
            for (int u = 0; u < 8; ++u) {
                int ed = __shfl(ed_i, j + u);
                bf16x2 v = *(const bf16x2*)(h + (size_t)(ed & 3) * (N_NODES * C)
                                              + (size_t)(ed >> 2) * C + c);
                t0 += (float)v[0];
                t1 += (float)v[1];
            }
            a0 += t0; a1 += t1;
        }
        for (; j + 4 <= cnt; j += 4) {
            int e0 = __shfl(ed_i, j);
            int e1 = __shfl(ed_i, j + 1);
            int e2 = __shfl(ed_i, j + 2);
            int e3 = __shfl(ed_i, j + 3);
            bf16x2 v0 = *(const bf16x2*)(h + (size_t)(e0 & 3) * (N_NODES * C) + (size_t)(e0 >> 2) * C + c);
            bf16x2 v1 = *(const bf16x2*)(h + (size_t)(e1 & 3) * (N_NODES * C) + (size_t)(e1 >> 2) * C + c);
            bf16x2 v2 = *(const bf16x2*)(h + (size_t)(e2 & 3) * (N_NODES * C) + (size_t)(e2 >> 2) * C + c);
            bf16x2 v3 = *(const bf16x2*)(h + (size_t)(e3 & 3) * (N_NODES * C) + (size_t)(e3 >> 2) * C + c);
            a0 += (float)v0[0] + (float)v1[0] + (float)v2[0] + (float)v3[0];
            a1 += (float)v0[1] + (float)v1[1] + (float)v2[1] + (float)v3[1];
        }
        for (; j < cnt; ++j) {
            int ed = __shfl(ed_i, j);
            bf16x2 v = *(const bf16x2*)(h + (size_t)(ed & 3) * (N_NODES * C) + (size_t)(ed >> 2) * C + c);
            a0 += (float)v[0];
            a1 += (float)v[1];
        }
    }

    if (flags[0]) {
        f32x2 o; o[0] = a0; o[1] = a1;
        *(f32x2*)((float*)out + (size_t)node * C + c) = o;
    } else {
        bf16x2 o; o[0] = (bf16)a0; o[1] = (bf16)a1;
        *(bf16x2*)((bf16*)out + (size_t)node * C + c) = o;
    }
}

// ---------------------------------------------------------------------------
extern "C" void kernel_launch(void* const* d_in, const int* in_sizes, int n_in,
                              void* d_out, int out_size, void* d_ws, size_t ws_size,
                              hipStream_t stream) {
    // 0 t | 1 node_embeddings [3,N,C] | 2 edge_index [2,E] | 3 edge_weights [E]
    // 4 loop_W1 5 loop_b1 6 loop_W2 7 loop_b2 | 8 rel_W1 9 rel_b1 10 rel_W2 11 rel_b2
    // 12 hh_W1 [2,C,C] 13 hh_b1 [2,C] 14 hh_W2 [2,C,C] 15 hh_b2 [2,C] | 16 hop_coef [3]
    const void* emb = d_in[1];
    const int*  ei  = (const int*)d_in[2];
    const int*  ew  = (const int*)d_in[3];

    // ws layout
    const size_t H_BYTES  = (size_t)3 * N_NODES * C * sizeof(bf16);   // 38.4 MB
    const size_t HS_BYTES = (size_t)N_NODES * C * sizeof(bf16);       // 12.8 MB
    const size_t PW_BYTES = (size_t)8 * 16384 * sizeof(bf16);         // 256 KB
    bf16*  h      = (bf16*)d_ws;
    bf16*  hs     = (bf16*)((char*)d_ws + H_BYTES);
    bf16*  pw     = (bf16*)((char*)d_ws + H_BYTES + HS_BYTES);
    float* cbias  = (float*)((char*)d_ws + H_BYTES + HS_BYTES + PW_BYTES);
    float* ccoef  = cbias + 1024;
    int*   flags  = (int*)(ccoef + 4);
    int*   deg    = flags + 16;
    int*   cursor = deg + N_NODES;
    int*   offsets= cursor + N_NODES;
    int*   btot   = offsets + N_NODES + 8;
    int*   bbase  = btot + 256;
    int*   edata  = bbase + 256;

    // pack slots: 0 rel_W1, 1 rel_W2, 2 hh_W1[0], 3 hh_W2[0], 4 hh_W1[1], 5 hh_W2[1], 6 loop_W1, 7 loop_W2
    PtrsV wptr;
    wptr.p[0] = d_in[8];   wptr.p[1] = d_in[10];
    wptr.p[2] = d_in[12];  wptr.p[3] = d_in[14];
    wptr.p[4] = d_in[12];  wptr.p[5] = d_in[14];   // +16384 elems inside pack
    wptr.p[6] = d_in[4];   wptr.p[7] = d_in[6];
    PtrsV bptr;
    bptr.p[0] = d_in[9];   bptr.p[1] = d_in[11];
    bptr.p[2] = d_in[13];  bptr.p[3] = d_in[15];
    bptr.p[4] = d_in[13];  bptr.p[5] = d_in[15];   // +128 inside pack
    bptr.p[6] = d_in[5];   bptr.p[7] = d_in[7];

    const int NBLK = (N_NODES + 255) / 256;   // 196

    detect_zero_kernel<<<1 + NBLK, 256, 0, stream>>>(
        (const unsigned short*)emb, (const unsigned short*)d_in[8],
        (const unsigned short*)d_in[9], (const unsigned short*)d_in[16],
        flags, deg);

    pack_kernel<<<517, 256, 0, stream>>>(wptr, bptr, d_in[16], flags, pw, cbias, ccoef);

    const int* erow = ei;
    const int* ecol = ei + N_EDGES;
    hist_kernel<<<(N_EDGES + 255) / 256, 256, 0, stream>>>(erow, deg);
    scanA_kernel<<<NBLK, 256, 0, stream>>>(deg, offsets, btot);
    scanB_kernel<<<1, 256, 0, stream>>>(btot, bbase, NBLK);
    scanC_kernel<<<NBLK, 256, 0, stream>>>(bbase, offsets, cursor);
    fill_kernel<<<(N_EDGES + 255) / 256, 256, 0, stream>>>(erow, ecol, ew, cursor, edata);

    // MLPs: 256 blocks (1/CU), task = blk&3, 8 waves x (3 pair-rounds + tail)
    mlp_kernel<<<MLP_BLOCKS, 512, 0, stream>>>(
        emb, pw, cbias, ccoef, flags, h, hs);

    gather_kernel<<<(N_NODES + 3) / 4, 256, 0, stream>>>(
        offsets, edata, h, hs, d_out, flags);
}

// Round 5
// 244.900 us; speedup vs baseline: 1.2131x; 1.0994x over previous
//
#include <hip/hip_runtime.h>

#define N_NODES 50000
#define N_EDGES 600000
#define C 128
#define STRIPS 3125          // N_NODES / 16
#define N_TASKS 4            // 0 rel(L2) 1 hh0(L1) 2 hh1(L0) 3 loop(L2)
#define MLP_BLOCKS 256       // 1 block/CU; task = blk&3
#define MAXOVF 16384         // overflow list capacity (expected use: 0)

typedef __bf16 bf16;
typedef __attribute__((ext_vector_type(8))) __bf16 bf16x8;
typedef __attribute__((ext_vector_type(4))) __bf16 bf16x4;
typedef __attribute__((ext_vector_type(2))) __bf16 bf16x2;
typedef __attribute__((ext_vector_type(4))) float f32x4;
typedef __attribute__((ext_vector_type(2))) float f32x2;

struct PtrsV { const void* p[8]; };

// ---------------------------------------------------------------------------
// Dtype detection (verified R2-R6) + cursor/deg zeroing. flags 1=fp32,0=bf16.
// ---------------------------------------------------------------------------
__device__ __forceinline__ int bf16_wild(unsigned short w) {
    int exp = (w >> 7) & 0xFF;
    int mant = w & 0x7F;
    if (exp == 0xFF) return 1;
    if (exp >= 133) return 1;                // |x| >= 64
    if (exp == 0) return mant != 0 ? 1 : 0;  // denormal
    if (exp <= 114) return 1;                // 0 < |x| < 2^-12
    return 0;
}

__global__ void __launch_bounds__(256) detect_zero_kernel(
    const unsigned short* __restrict__ emb,
    const unsigned short* __restrict__ w,
    const unsigned short* __restrict__ b,
    const unsigned short* __restrict__ hc,
    int* __restrict__ flags,
    int* __restrict__ z0, int* __restrict__ z1,   // cursor / deg (may alias)
    int* __restrict__ ovf_cnt)
{
    if (blockIdx.x == 0) {
        int lane = threadIdx.x;
        if (lane >= 64) return;
        int ce = 0, cw = 0, cb = 0, ch = 0;
        for (int j = 0; j < 4; ++j) {
            ce += bf16_wild(emb[lane * 4 + j]);
            cw += bf16_wild(w[lane * 4 + j]);
        }
        for (int j = 0; j < 2; ++j) cb += bf16_wild(b[lane * 2 + j]);
        if (lane < 3) ch = bf16_wild(hc[lane]);
        for (int off = 32; off > 0; off >>= 1) {
            ce += __shfl_down(ce, off);
            cw += __shfl_down(cw, off);
            cb += __shfl_down(cb, off);
            ch += __shfl_down(ch, off);
        }
        if (lane == 0) {
            int wf = (cw >= 16) ? 1 : 0;
            flags[0] = (ce >= 16) ? 1 : 0;
            flags[1] = wf;
            flags[2] = (cb >= 8) ? 1 : 0;
            flags[3] = (ch > 0) ? 1 : wf;
        }
    } else {
        int i = (blockIdx.x - 1) * 256 + threadIdx.x;
        if (i < N_NODES) { z0[i] = 0; z1[i] = 0; }
        if (blockIdx.x == 1 && threadIdx.x == 0) *ovf_cnt = 0;
    }
}

// ---------------------------------------------------------------------------
// Pack weights into MFMA B-fragment order (verified R2-R6).
// Frag index within matrix (as bf16x8): kk*512 + n0*64 + lane.
// Slots 4,5 are the second hh matrix (+16384 elems / +128 bias).
// ---------------------------------------------------------------------------
__global__ void __launch_bounds__(256) pack_kernel(
    PtrsV wmats, PtrsV bvecs, const void* hc_raw,
    const int* __restrict__ flags,
    bf16* __restrict__ pw, float* __restrict__ cbias, float* __restrict__ ccoef)
{
    int tid = blockIdx.x * 256 + threadIdx.x;
    int wf = flags[1], bfl = flags[2], hf = flags[3];
    if (tid < 8 * 16384) {
        int m    = tid >> 14;
        int r    = tid & 16383;
        int j    = r & 7;
        int lane = (r >> 3) & 63;
        int n0   = (r >> 9) & 7;
        int kk   = r >> 12;
        int k = kk * 32 + (lane >> 4) * 8 + j;
        int n = n0 * 16 + (lane & 15);
        int idx = k * C + n + ((m == 4 || m == 5) ? 16384 : 0);
        float v = wf ? ((const float*)wmats.p[m])[idx]
                     : (float)((const bf16*)wmats.p[m])[idx];
        pw[tid] = (bf16)v;
    } else if (tid < 8 * 16384 + 1024) {
        int j = tid - 8 * 16384;
        int m = j >> 7, n = j & 127;
        int idx = n + ((m == 4 || m == 5) ? 128 : 0);
        float v = bfl ? ((const float*)bvecs.p[m])[idx]
                      : (float)((const bf16*)bvecs.p[m])[idx];
        cbias[j] = v;
    } else if (tid < 8 * 16384 + 1024 + 3) {
        int i = tid - (8 * 16384 + 1024);
        float v = hf ? ((const float*)hc_raw)[i]
                     : (float)((const bf16*)hc_raw)[i];
        ccoef[i] = v;
    }
}

// ---------------------------------------------------------------------------
// MLP v7 (R9 structure, measured 46us; R10's 2-strip variant regressed to
// 50us so reverted). One task per block, 512 threads, task's 64KB packed
// weights staged in LDS once, waves loop over strips with A prefetched one
// strip ahead. LDS 64KB + 8*4.25KB = 100KB -> 1 block/CU.
// ---------------------------------------------------------------------------
__global__ __launch_bounds__(512, 2) void mlp_kernel(
    const void* __restrict__ emb_raw,    // [3][N][C] fp32 or bf16
    const bf16* __restrict__ pw,         // packed weights [8][16384]
    const float* __restrict__ cbias,     // [8][128]
    const float* __restrict__ ccoef,     // [3]
    const int* __restrict__ flags,
    bf16* __restrict__ h,                // [3][N][C], premultiplied by coef
    bf16* __restrict__ hs)               // [N][C] self term (loop MLP)
{
    __shared__ bf16 sW[32768];           // 64 KB: W1 then W2 fragments (this task)
    __shared__ bf16 sH[8][16][136];      // 34.8 KB: per-wave transpose buffer
    const int tid  = threadIdx.x;
    const int wave = tid >> 6, lane = tid & 63;
    const int task  = blockIdx.x & 3;
    const int bslot = blockIdx.x >> 2;          // 0..63
    const int lrow = lane & 15, lquad = lane >> 4;
    bf16 (*sh)[136] = sH[wave];

    const int m1_of[4] = {0, 2, 4, 6};
    const int ly_of[4] = {2, 1, 0, 2};
    const int m1 = m1_of[task];
    const float oscale = (task == 0) ? ccoef[0] : (task == 1) ? ccoef[1]
                       : (task == 2) ? ccoef[2] : 1.0f;
    bf16* outp = (task == 3) ? hs : (h + (size_t)task * N_NODES * C);
    const int emb_f32 = flags[0];
    const size_t lbase = (size_t)ly_of[task] * N_NODES * C;

    // ---- stage this task's weights into LDS (64 KB = 4096 x 16B) ----
    {
        const f32x4* src = (const f32x4*)(pw + (size_t)m1 * 16384);
        f32x4* dst = (f32x4*)sW;
        #pragma unroll
        for (int i = 0; i < 8; ++i)
            dst[i * 512 + tid] = src[i * 512 + tid];
    }
    __syncthreads();
    const bf16x8* w1v = (const bf16x8*)sW;      // frag (kk*512 + n0*64 + lane)
    const bf16x8* w2v = w1v + 2048;

    // ---- biases for this lane's columns ----
    float b1f[8], b2f[8];
    #pragma unroll
    for (int n0 = 0; n0 < 8; ++n0) {
        b1f[n0] = cbias[m1 * 128 + n0 * 16 + lrow];
        b2f[n0] = cbias[(m1 + 1) * 128 + n0 * 16 + lrow];
    }

    // ---- strip loop: slot-strided, A prefetched one strip ahead ----
    int s = bslot * 8 + wave;                   // 0..511
    f32x4 u[8]; bf16x8 araw[4];

    // prologue: issue raw A loads for first strip
    {
        size_t xb = lbase + (size_t)(s * 16 + lrow) * C + lquad * 8;
        if (emb_f32) {
            const float* xf = (const float*)emb_raw + xb;
            #pragma unroll
            for (int kk = 0; kk < 4; ++kk) {
                u[kk * 2]     = *(const f32x4*)(xf + kk * 32);
                u[kk * 2 + 1] = *(const f32x4*)(xf + kk * 32 + 4);
            }
        } else {
            const bf16* x16 = (const bf16*)emb_raw + xb;
            #pragma unroll
            for (int kk = 0; kk < 4; ++kk)
                araw[kk] = *(const bf16x8*)(x16 + kk * 32);
        }
    }

    while (s < STRIPS) {
        const int snext = s + 512;

        // convert raw -> af (frees the raw buffers for the prefetch)
        bf16x8 af[4];
        if (emb_f32) {
            #pragma unroll
            for (int kk = 0; kk < 4; ++kk) {
                f32x4 u0 = u[kk * 2], u1 = u[kk * 2 + 1];
                bf16x8 v;
                v[0]=(bf16)u0[0]; v[1]=(bf16)u0[1]; v[2]=(bf16)u0[2]; v[3]=(bf16)u0[3];
                v[4]=(bf16)u1[0]; v[5]=(bf16)u1[1]; v[6]=(bf16)u1[2]; v[7]=(bf16)u1[3];
                af[kk] = v;
            }
        } else {
            #pragma unroll
            for (int kk = 0; kk < 4; ++kk) af[kk] = araw[kk];
        }

        // issue raw A loads for the NEXT strip (in flight during GEMMs)
        if (snext < STRIPS) {
            size_t xb = lbase + (size_t)(snext * 16 + lrow) * C + lquad * 8;
            if (emb_f32) {
                const float* xf = (const float*)emb_raw + xb;
                #pragma unroll
                for (int kk = 0; kk < 4; ++kk) {
                    u[kk * 2]     = *(const f32x4*)(xf + kk * 32);
                    u[kk * 2 + 1] = *(const f32x4*)(xf + kk * 32 + 4);
                }
            } else {
                const bf16* x16 = (const bf16*)emb_raw + xb;
                #pragma unroll
                for (int kk = 0; kk < 4; ++kk)
                    araw[kk] = *(const bf16x8*)(x16 + kk * 32);
            }
        }

        // ---- GEMM1: hidden = relu(X @ W1 + b1) -> sh, B from LDS ----
        #pragma unroll
        for (int n0 = 0; n0 < 8; ++n0) {
            bf16x8 bv0 = w1v[0 * 512 + n0 * 64 + lane];
            bf16x8 bv1 = w1v[1 * 512 + n0 * 64 + lane];
            bf16x8 bv2 = w1v[2 * 512 + n0 * 64 + lane];
            bf16x8 bv3 = w1v[3 * 512 + n0 * 64 + lane];
            int n = n0 * 16 + lrow;
            float bias = b1f[n0];
            f32x4 a4 = {0.f, 0.f, 0.f, 0.f};
            a4 = __builtin_amdgcn_mfma_f32_16x16x32_bf16(af[0], bv0, a4, 0, 0, 0);
            a4 = __builtin_amdgcn_mfma_f32_16x16x32_bf16(af[1], bv1, a4, 0, 0, 0);
            a4 = __builtin_amdgcn_mfma_f32_16x16x32_bf16(af[2], bv2, a4, 0, 0, 0);
            a4 = __builtin_amdgcn_mfma_f32_16x16x32_bf16(af[3], bv3, a4, 0, 0, 0);
            #pragma unroll
            for (int r = 0; r < 4; ++r) {
                float v = a4[r] + bias;
                v = v > 0.f ? v : 0.f;
                sh[lquad * 4 + r][n] = (bf16)v;
            }
        }

        // ---- read GEMM2 A-frags (in-wave LDS RAW, compiler-ordered) ----
        bf16x8 ah[4];
        #pragma unroll
        for (int kk = 0; kk < 4; ++kk)
            ah[kk] = *(const bf16x8*)(&sh[lrow][kk * 32 + lquad * 8]);

        // ---- GEMM2: out = oscale*(hidden @ W2 + b2) -> sh ----
        #pragma unroll
        for (int n0 = 0; n0 < 8; ++n0) {
            bf16x8 bv0 = w2v[0 * 512 + n0 * 64 + lane];
            bf16x8 bv1 = w2v[1 * 512 + n0 * 64 + lane];
            bf16x8 bv2 = w2v[2 * 512 + n0 * 64 + lane];
            bf16x8 bv3 = w2v[3 * 512 + n0 * 64 + lane];
            int n = n0 * 16 + lrow;
            float bias = b2f[n0];
            f32x4 a4 = {0.f, 0.f, 0.f, 0.f};
            a4 = __builtin_amdgcn_mfma_f32_16x16x32_bf16(ah[0], bv0, a4, 0, 0, 0);
            a4 = __builtin_amdgcn_mfma_f32_16x16x32_bf16(ah[1], bv1, a4, 0, 0, 0);
            a4 = __builtin_amdgcn_mfma_f32_16x16x32_bf16(ah[2], bv2, a4, 0, 0, 0);
            a4 = __builtin_amdgcn_mfma_f32_16x16x32_bf16(ah[3], bv3, a4, 0, 0, 0);
            #pragma unroll
            for (int r = 0; r < 4; ++r)
                sh[lquad * 4 + r][n] = (bf16)((a4[r] + bias) * oscale);
        }

        // ---- coalesced store of 16 rows ----
        {
            int row = lane >> 2;
            int cs  = (lane & 3) * 32;
            bf16* dst = outp + (size_t)(s * 16) * C;
            #pragma unroll
            for (int j = 0; j < 4; ++j) {
                bf16x8 v = *(const bf16x8*)(&sh[row][cs + j * 8]);
                *(bf16x8*)(dst + (size_t)row * C + cs + j * 8) = v;
            }
        }

        s = snext;
    }
}

// ---------------------------------------------------------------------------
// R11 bucket path: single edge pass replaces hist+scanA/B/C+fill (5 launches,
// 1.2M atomics -> 1 launch, 600k atomics). Fixed-capacity per-node buckets;
// degrees are Poisson(12) so cap>=32 overflows w.p. ~1e-6; overflow list +
// post-gather CAS-add kernel keeps exactness for any input.
// ---------------------------------------------------------------------------
__global__ void __launch_bounds__(256) bucket_kernel(
    const int* __restrict__ erow, const int* __restrict__ ecol,
    const int* __restrict__ ew,
    int* __restrict__ cursor, int* __restrict__ edata,
    int* __restrict__ ovf_cnt, int* __restrict__ ovf, int cap)
{
    int e = blockIdx.x * 256 + threadIdx.x;
    if (e >= N_EDGES) return;
    int dst = erow[e];
    int val = (ecol[e] << 2) | (ew[e] - 1);
    int pos = atomicAdd(&cursor[dst], 1);
    if (pos < cap) {
        edata[(size_t)dst * cap + pos] = val;
    } else {
        int o = atomicAdd(ovf_cnt, 1);
        if (o < MAXOVF) { ovf[2 * o] = dst; ovf[2 * o + 1] = val; }
    }
}

// ---------------------------------------------------------------------------
// CSR fallback path (verified R5/R6) — used only if workspace is too small
// for buckets. hist + 3-phase scan + fill.
// ---------------------------------------------------------------------------
__global__ void __launch_bounds__(256) hist_kernel(
    const int* __restrict__ erow, int* __restrict__ deg)
{
    int e = blockIdx.x * 256 + threadIdx.x;
    if (e >= N_EDGES) return;
    atomicAdd(&deg[erow[e]], 1);
}

__device__ __forceinline__ int wave_incl_scan(int v, int lane) {
    int x = v;
    #pragma unroll
    for (int d = 1; d < 64; d <<= 1) {
        int t = __shfl_up(x, d);
        if (lane >= d) x += t;
    }
    return x;
}

__global__ void __launch_bounds__(256) scanA_kernel(
    const int* __restrict__ deg, int* __restrict__ offsets, int* __restrict__ btot)
{
    __shared__ int swave[4];
    int b = blockIdx.x, tid = threadIdx.x;
    int i = b * 256 + tid;
    int lane = tid & 63, wv = tid >> 6;
    int v = (i < N_NODES) ? deg[i] : 0;
    int x = wave_incl_scan(v, lane);
    if (lane == 63) swave[wv] = x;
    __syncthreads();
    int w0 = swave[0], w1 = swave[1], w2 = swave[2], w3 = swave[3];
    int wp = (wv > 0 ? w0 : 0) + (wv > 1 ? w1 : 0) + (wv > 2 ? w2 : 0);
    if (i < N_NODES) offsets[i] = wp + x - v;
    if (tid == 0) btot[b] = w0 + w1 + w2 + w3;
}

__global__ void __launch_bounds__(256) scanB_kernel(
    const int* __restrict__ btot, int* __restrict__ bbase, int nblk)
{
    __shared__ int swave[4];
    int tid = threadIdx.x;
    int lane = tid & 63, wv = tid >> 6;
    int v = (tid < nblk) ? btot[tid] : 0;
    int x = wave_incl_scan(v, lane);
    if (lane == 63) swave[wv] = x;
    __syncthreads();
    int w0 = swave[0], w1 = swave[1], w2 = swave[2], w3 = swave[3];
    int wp = (wv > 0 ? w0 : 0) + (wv > 1 ? w1 : 0) + (wv > 2 ? w2 : 0);
    if (tid < nblk) bbase[tid] = wp + x - v;
}

__global__ void __launch_bounds__(256) scanC_kernel(
    const int* __restrict__ bbase, int* __restrict__ offsets, int* __restrict__ cursor)
{
    int i = blockIdx.x * 256 + threadIdx.x;
    if (i < N_NODES) {
        int o = offsets[i] + bbase[blockIdx.x];
        offsets[i] = o;
        cursor[i] = o;
    }
    if (i == 0) offsets[N_NODES] = N_EDGES;
}

__global__ void __launch_bounds__(256) fill_kernel(
    const int* __restrict__ erow, const int* __restrict__ ecol,
    const int* __restrict__ ew,
    int* __restrict__ cursor, int* __restrict__ edata)
{
    int e = blockIdx.x * 256 + threadIdx.x;
    if (e >= N_EDGES) return;
    int dst = erow[e];
    int pos = atomicAdd(&cursor[dst], 1);
    edata[pos] = (ecol[e] << 2) | (ew[e] - 1);
}

// ---------------------------------------------------------------------------
// Gather: one wave per node, lane = 2 channels; h coef-premultiplied so the
// inner op is a plain add. cap>0: bucket mode (edata[node*cap], deg=cursor);
// cap==0: CSR mode (offsets segments). 8/4/1 unroll cascade for load ILP.
// ---------------------------------------------------------------------------
__global__ void __launch_bounds__(256) gather_kernel(
    const int* __restrict__ offsets, const int* __restrict__ cursor,
    const int* __restrict__ edata,
    const bf16* __restrict__ h,          // [3][N][C]
    const bf16* __restrict__ hs,         // [N][C]
    void* __restrict__ out,
    const int* __restrict__ flags, int cap)
{
    const int node = blockIdx.x * 4 + (threadIdx.x >> 6);
    if (node >= N_NODES) return;
    const int lane = threadIdx.x & 63;
    const int c = lane * 2;

    bf16x2 sv = *(const bf16x2*)(hs + (size_t)node * C + c);
    float a0 = (float)sv[0], a1 = (float)sv[1];

    int s, e;
    const int* ebase;
    if (cap) {
        int d = cursor[node];
        if (d > cap) d = cap;
        s = 0; e = d;
        ebase = edata + (size_t)node * cap;
    } else {
        s = offsets[node]; e = offsets[node + 1];
        ebase = edata;
    }

    for (int base = s; base < e; base += 64) {
        int idx = base + lane;
        int ed_i = (idx < e) ? ebase[idx] : 0;
        int cnt = e - base; if (cnt > 64) cnt = 64;
        int j = 0;
        for (; j + 8 <= cnt; j += 8) {
            float t0 = 0.f, t1 = 0.f;
            #pragma unroll
            for (int u = 0; u < 8; ++u) {
                int ed = __shfl(ed_i, j + u);
                bf16x2 v = *(const bf16x2*)(h + (size_t)(ed & 3) * (N_NODES * C)
                                              + (size_t)(ed >> 2) * C + c);
                t0 += (float)v[0];
                t1 += (float)v[1];
            }
            a0 += t0; a1 += t1;
        }
        for (; j + 4 <= cnt; j += 4) {
            int e0 = __shfl(ed_i, j);
            int e1 = __shfl(ed_i, j + 1);
            int e2 = __shfl(ed_i, j + 2);
            int e3 = __shfl(ed_i, j + 3);
            bf16x2 v0 = *(const bf16x2*)(h + (size_t)(e0 & 3) * (N_NODES * C) + (size_t)(e0 >> 2) * C + c);
            bf16x2 v1 = *(const bf16x2*)(h + (size_t)(e1 & 3) * (N_NODES * C) + (size_t)(e1 >> 2) * C + c);
            bf16x2 v2 = *(const bf16x2*)(h + (size_t)(e2 & 3) * (N_NODES * C) + (size_t)(e2 >> 2) * C + c);
            bf16x2 v3 = *(const bf16x2*)(h + (size_t)(e3 & 3) * (N_NODES * C) + (size_t)(e3 >> 2) * C + c);
            a0 += (float)v0[0] + (float)v1[0] + (float)v2[0] + (float)v3[0];
            a1 += (float)v0[1] + (float)v1[1] + (float)v2[1] + (float)v3[1];
        }
        for (; j < cnt; ++j) {
            int ed = __shfl(ed_i, j);
            bf16x2 v = *(const bf16x2*)(h + (size_t)(ed & 3) * (N_NODES * C) + (size_t)(ed >> 2) * C + c);
            a0 += (float)v[0];
            a1 += (float)v[1];
        }
    }

    if (flags[0]) {
        f32x2 o; o[0] = a0; o[1] = a1;
        *(f32x2*)((float*)out + (size_t)node * C + c) = o;
    } else {
        bf16x2 o; o[0] = (bf16)a0; o[1] = (bf16)a1;
        *(bf16x2*)((bf16*)out + (size_t)node * C + c) = o;
    }
}

// ---------------------------------------------------------------------------
// Overflow gather: adds overflowed edges into out (runs after gather; stream
// order guarantees no race with gather's plain stores). Expected 0 entries.
// ---------------------------------------------------------------------------
__device__ __forceinline__ float bf2f(unsigned short s) {
    unsigned int u = (unsigned int)s << 16;
    float f; __builtin_memcpy(&f, &u, 4); return f;
}
__device__ __forceinline__ unsigned short f2bf(float f) {
    bf16 b = (bf16)f;
    unsigned short s; __builtin_memcpy(&s, &b, 2); return s;
}

__global__ void __launch_bounds__(256) ovf_kernel(
    const int* __restrict__ ovf_cnt, const int* __restrict__ ovf,
    const bf16* __restrict__ h, void* __restrict__ out,
    const int* __restrict__ flags)
{
    int n = *ovf_cnt; if (n > MAXOVF) n = MAXOVF;
    if (n <= 0) return;
    const int gw = (blockIdx.x * 256 + threadIdx.x) >> 6;
    const int lane = threadIdx.x & 63;
    const int nw = gridDim.x * 4;
    const int c = lane * 2;
    for (int i = gw; i < n; i += nw) {
        int dst = ovf[2 * i], val = ovf[2 * i + 1];
        bf16x2 v = *(const bf16x2*)(h + (size_t)(val & 3) * (N_NODES * C)
                                      + (size_t)(val >> 2) * C + c);
        float v0 = (float)v[0], v1 = (float)v[1];
        if (flags[0]) {
            atomicAdd((float*)out + (size_t)dst * C + c, v0);
            atomicAdd((float*)out + (size_t)dst * C + c + 1, v1);
        } else {
            unsigned int* p = (unsigned int*)((bf16*)out + (size_t)dst * C + c);
            unsigned int old = *p, assumed;
            do {
                assumed = old;
                unsigned short lo = assumed & 0xFFFF, hi = assumed >> 16;
                unsigned int nb = (unsigned int)f2bf(bf2f(lo) + v0)
                                | ((unsigned int)f2bf(bf2f(hi) + v1) << 16);
                old = atomicCAS(p, assumed, nb);
            } while (old != assumed);
        }
    }
}

// ---------------------------------------------------------------------------
extern "C" void kernel_launch(void* const* d_in, const int* in_sizes, int n_in,
                              void* d_out, int out_size, void* d_ws, size_t ws_size,
                              hipStream_t stream) {
    // 0 t | 1 node_embeddings [3,N,C] | 2 edge_index [2,E] | 3 edge_weights [E]
    // 4 loop_W1 5 loop_b1 6 loop_W2 7 loop_b2 | 8 rel_W1 9 rel_b1 10 rel_W2 11 rel_b2
    // 12 hh_W1 [2,C,C] 13 hh_b1 [2,C] 14 hh_W2 [2,C,C] 15 hh_b2 [2,C] | 16 hop_coef [3]
    const void* emb = d_in[1];
    const int*  ei  = (const int*)d_in[2];
    const int*  ew  = (const int*)d_in[3];

    // ---- ws layout (common prefix) ----
    char* base = (char*)d_ws;
    bf16*  h      = (bf16*)base;                          // 38,400,000
    bf16*  hs     = (bf16*)(base + 38400000);             // 12,800,000
    bf16*  pw     = (bf16*)(base + 51200000);             //    262,144
    float* cbias  = (float*)(base + 51462144);            //      4,096
    float* ccoef  = (float*)(base + 51466240);            //         16
    int*   flags  = (int*)(base + 51466256);              //         32 (4 used)
    int*   ovf_cnt= (int*)(base + 51466288);              //         64
    int*   cursor = (int*)(base + 51466752);              //    200,000 -> 51,666,752

    // bucket-mode tail: ovf list + strided edata
    int*   ovf    = (int*)(base + 51666752);              // 131,072 -> 51,797,824
    int*   bedata = (int*)(base + 51797824);
    size_t avail  = ws_size > 51797824 ? ws_size - 51797824 : 0;
    int cap = (int)(avail / (4ull * N_NODES));
    if (cap > 96) cap = 96;
    cap &= ~15;                                           // bucket mode iff cap>=32

    // CSR-mode tail (fallback, same footprint as R6-R10 layout)
    int*   deg    = (int*)(base + 51666752);              //    200,000
    int*   offsets= (int*)(base + 51866752);              //    200,064
    int*   btot   = (int*)(base + 52066816);              //      1,024
    int*   bbase  = (int*)(base + 52067840);              //      1,024
    int*   cedata = (int*)(base + 52068864);              //  2,400,000 -> 54.47MB

    // pack slots: 0 rel_W1, 1 rel_W2, 2 hh_W1[0], 3 hh_W2[0], 4 hh_W1[1], 5 hh_W2[1], 6 loop_W1, 7 loop_W2
    PtrsV wptr;
    wptr.p[0] = d_in[8];   wptr.p[1] = d_in[10];
    wptr.p[2] = d_in[12];  wptr.p[3] = d_in[14];
    wptr.p[4] = d_in[12];  wptr.p[5] = d_in[14];   // +16384 elems inside pack
    wptr.p[6] = d_in[4];   wptr.p[7] = d_in[6];
    PtrsV bptr;
    bptr.p[0] = d_in[9];   bptr.p[1] = d_in[11];
    bptr.p[2] = d_in[13];  bptr.p[3] = d_in[15];
    bptr.p[4] = d_in[13];  bptr.p[5] = d_in[15];   // +128 inside pack
    bptr.p[6] = d_in[5];   bptr.p[7] = d_in[7];

    const int NBLK = (N_NODES + 255) / 256;   // 196
    const int EBLK = (N_EDGES + 255) / 256;
    const int* erow = ei;
    const int* ecol = ei + N_EDGES;

    if (cap >= 32) {
        // ---- bucket path: 6 launches ----
        detect_zero_kernel<<<1 + NBLK, 256, 0, stream>>>(
            (const unsigned short*)emb, (const unsigned short*)d_in[8],
            (const unsigned short*)d_in[9], (const unsigned short*)d_in[16],
            flags, cursor, cursor, ovf_cnt);

        pack_kernel<<<517, 256, 0, stream>>>(wptr, bptr, d_in[16], flags, pw, cbias, ccoef);

        bucket_kernel<<<EBLK, 256, 0, stream>>>(erow, ecol, ew, cursor, bedata,
                                                ovf_cnt, ovf, cap);

        mlp_kernel<<<MLP_BLOCKS, 512, 0, stream>>>(emb, pw, cbias, ccoef, flags, h, hs);

        gather_kernel<<<(N_NODES + 3) / 4, 256, 0, stream>>>(
            cursor, cursor, bedata, h, hs, d_out, flags, cap);

        ovf_kernel<<<32, 256, 0, stream>>>(ovf_cnt, ovf, h, d_out, flags);
    } else {
        // ---- CSR fallback: verified R6-R10 path ----
        detect_zero_kernel<<<1 + NBLK, 256, 0, stream>>>(
            (const unsigned short*)emb, (const unsigned short*)d_in[8],
            (const unsigned short*)d_in[9], (const unsigned short*)d_in[16],
            flags, deg, deg, ovf_cnt);

        pack_kernel<<<517, 256, 0, stream>>>(wptr, bptr, d_in[16], flags, pw, cbias, ccoef);

        hist_kernel<<<EBLK, 256, 0, stream>>>(erow, deg);
        scanA_kernel<<<NBLK, 256, 0, stream>>>(deg, offsets, btot);
        scanB_kernel<<<1, 256, 0, stream>>>(btot, bbase, NBLK);
        scanC_kernel<<<NBLK, 256, 0, stream>>>(bbase, offsets, cursor);
        fill_kernel<<<EBLK, 256, 0, stream>>>(erow, ecol, ew, cursor, cedata);

        mlp_kernel<<<MLP_BLOCKS, 512, 0, stream>>>(emb, pw, cbias, ccoef, flags, h, hs);

        gather_kernel<<<(N_NODES + 3) / 4, 256, 0, stream>>>(
            offsets, cursor, cedata, h, hs, d_out, flags, 0);
    }
}